// Round 15
// baseline (255.477 us; speedup 1.0000x reference)
//
#include <hip/hip_runtime.h>
#include <math.h>

#define D_MODEL 768
#define D_STATE 16
#define D_INNER 1536
#define DT_RANK 48
#define B_SZ    2
#define L_SEQ   2048
#define CH      32             // scan chunk length
#define NCH     (L_SEQ / CH)   // 64 chunks
#define NDG     24             // d-groups of 64 channels
#define MTOT    (B_SZ * L_SEQ) // 4096
#define LOG2E   1.4426950408889634f
#define LN2     0.6931471805599453f

typedef __bf16 bf16x8 __attribute__((ext_vector_type(8)));
typedef float f32x4 __attribute__((ext_vector_type(4)));
typedef ushort ushort8_t __attribute__((ext_vector_type(8)));

__device__ __forceinline__ float ex2(float x) {
  return __builtin_amdgcn_exp2f(x);  // v_exp_f32: D = 2^S0
}

__device__ __forceinline__ ushort f2bf(float f) {
  unsigned int u = __float_as_uint(f);
  unsigned int r = (u + 0x7fff + ((u >> 16) & 1)) >> 16;
  return (ushort)r;
}
__device__ __forceinline__ float bf2f(ushort u) {
  return __uint_as_float(((unsigned int)u) << 16);
}

__device__ __forceinline__ void gload_lds16(const ushort* g, ushort* l) {
  __builtin_amdgcn_global_load_lds(
      (__attribute__((address_space(1))) void*)(void*)(g),
      (__attribute__((address_space(3))) void*)(void*)(l), 16, 0, 0);
}

// fast softplus: ln(1+e^x) = ln2 * log2(1 + 2^(x*log2e)); guard large x
__device__ __forceinline__ float softplus_fast(float x) {
  return (x > 20.f) ? x : LN2 * __log2f(1.f + ex2(x * LOG2E));
}

// ---------------------------------------------------------------------------
// bf16 MFMA GEMM body, double-buffered 2-phase K-loop.
// C[M,N] = A[M,K] * B[N,K]^T (+bias, +softplus). OBF: bf16 C. DTOUT: emit
// dtin bf16 (cols 0..47 -> k0, 80..127 -> k1, pad 64) + bcbuf FP32
// ([2][M][32]: B=cols 48..63/128..143, C=cols 64..79/144..159).
// ---------------------------------------------------------------------------
template <int BM, int BN, int ACT, int OBF, int DTOUT>
__device__ __forceinline__ void gemm_body(
    const ushort* __restrict__ A, int lda, const ushort* __restrict__ B,
    int ldb, const float* __restrict__ bias, void* __restrict__ Cp, int ldc,
    int Nreal, int K, int bxi, int byi, ushort* __restrict__ dtin,
    float* __restrict__ bcp) {
  __shared__ ushort As[2][BM][32];
  __shared__ ushort Bs[2][BN][32];
  constexpr int WM = BM / 2, WN = BN / 2;
  constexpr int FM = WM / 16, FN = WN / 16;
  const int tid = threadIdx.x;
  const int lane = tid & 63;
  const int w = tid >> 6;
  const int wr = w >> 1, wc = w & 1;
  const int bm = byi * BM, bn = bxi * BN;
  const int lrow = lane >> 2;
  const int lchunk = lane & 3;
  const int fr = lane & 15;
  const int k8 = (lane >> 4) * 8;

  f32x4 acc[FM][FN] = {};

  auto stage = [&](int buf, int k0) {
    if constexpr (BM >= 64) {
#pragma unroll
      for (int g = 0; g < BM / 64; ++g) {
        const int rb = w * (BM / 4) + g * 16;
        gload_lds16(A + (size_t)(bm + rb + lrow) * lda + k0 + lchunk * 8,
                    &As[buf][rb][0]);
      }
    } else {  // BM == 32
      if (w < 2)
        gload_lds16(A + (size_t)(bm + w * 16 + lrow) * lda + k0 + lchunk * 8,
                    &As[buf][w * 16][0]);
    }
#pragma unroll
    for (int g = 0; g < BN / 64; ++g) {
      const int rb = w * (BN / 4) + g * 16;
      gload_lds16(B + (size_t)(bn + rb + lrow) * ldb + k0 + lchunk * 8,
                  &Bs[buf][rb][0]);
    }
  };

  stage(0, 0);
  __syncthreads();
  int cur = 0;
  for (int k0 = 0; k0 < K; k0 += 32) {
    if (k0 + 32 < K) stage(cur ^ 1, k0 + 32);
    bf16x8 af[FM], bfr[FN];
#pragma unroll
    for (int m = 0; m < FM; ++m)
      af[m] =
          *reinterpret_cast<const bf16x8*>(&As[cur][wr * WM + m * 16 + fr][k8]);
#pragma unroll
    for (int n = 0; n < FN; ++n)
      bfr[n] =
          *reinterpret_cast<const bf16x8*>(&Bs[cur][wc * WN + n * 16 + fr][k8]);
#pragma unroll
    for (int m = 0; m < FM; ++m)
#pragma unroll
      for (int n = 0; n < FN; ++n)
        acc[m][n] = __builtin_amdgcn_mfma_f32_16x16x32_bf16(af[m], bfr[n],
                                                            acc[m][n], 0, 0, 0);
    __syncthreads();
    cur ^= 1;
  }

  const int row4 = (lane >> 4) * 4;
#pragma unroll
  for (int m = 0; m < FM; ++m) {
#pragma unroll
    for (int n = 0; n < FN; ++n) {
      const int gn = bn + wc * WN + n * 16 + fr;
      const int gm0 = bm + wr * WM + m * 16 + row4;
#pragma unroll
      for (int j = 0; j < 4; ++j) {
        const float v = acc[m][n][j];
        const int gm = gm0 + j;
        if (DTOUT) {
          if (gn < 64)
            dtin[(size_t)gm * 64 + gn] = (gn < 48) ? f2bf(v) : (ushort)0;
          else if (gn >= 80 && gn < 144)
            dtin[(size_t)MTOT * 64 + (size_t)gm * 64 + (gn - 80)] =
                (gn < 128) ? f2bf(v) : (ushort)0;
          if (gn >= 48 && gn < 80)
            bcp[(size_t)gm * 32 + (gn - 48)] = v;
          else if (gn >= 128 && gn < 160)
            bcp[(size_t)MTOT * 32 + (size_t)gm * 32 + (gn - 128)] = v;
        }
        if (gn < Nreal) {
          float vv = v + (bias ? bias[gn] : 0.f);
          if (ACT == 1) vv = softplus_fast(vv);
          if (OBF)
            ((ushort*)Cp)[(size_t)gm * ldc + gn] = f2bf(vv);
          else
            ((float*)Cp)[(size_t)gm * ldc + gn] = vv;
        }
      }
    }
  }
}

template <int BM, int BN, int ACT, int OBF, int DTOUT>
__global__ __launch_bounds__(256) void gemm_k(
    const ushort* __restrict__ A, int lda, const ushort* __restrict__ B,
    int ldb, const float* __restrict__ bias, void* __restrict__ Cp, int ldc,
    int Nreal, int K, ushort* __restrict__ dtin, float* __restrict__ bcp) {
  gemm_body<BM, BN, ACT, OBF, DTOUT>(A, lda, B, ldb, bias, Cp, ldc, Nreal, K,
                                     blockIdx.x, blockIdx.y, dtin, bcp);
}

// dt_proj both directions in one dispatch (blockIdx.z = k); 64x128 tile
__global__ __launch_bounds__(256) void gemm_dt_k(
    const ushort* __restrict__ dtin, const ushort* __restrict__ w_dt,
    const float* __restrict__ dtb, ushort* __restrict__ delta) {
  const int k = blockIdx.z;
  gemm_body<64, 128, 1, 1, 0>(
      dtin + (size_t)k * MTOT * 64, 64, w_dt + (size_t)k * D_INNER * 64, 64,
      dtb + k * D_INNER, delta + (size_t)k * MTOT * D_INNER, D_INNER, D_INNER,
      64, blockIdx.x, blockIdx.y, nullptr, nullptr);
}

// ---------------------------------------------------------------------------
// One-shot fp32->bf16 conversion of x + all weights (with padding).
// ---------------------------------------------------------------------------
__global__ __launch_bounds__(256) void cvt_all_kernel(
    const float* __restrict__ x, const float* __restrict__ w_in,
    const float* __restrict__ w_out, const float* __restrict__ w_xp,
    const float* __restrict__ w_dt, ushort* __restrict__ x_bf,
    ushort* __restrict__ w_in_bf, ushort* __restrict__ w_out_bf,
    ushort* __restrict__ w_xp_bf, ushort* __restrict__ w_dt_bf) {
  const long N0 = 3145728, N1 = 2359296, N2 = 1179648, N3 = 393216, N4 = 196608;
  long i = ((long)blockIdx.x * 256 + threadIdx.x) * 4;
  if (i < N0) {
    const float4 v = *(const float4*)(x + i);
    ushort4 o = {f2bf(v.x), f2bf(v.y), f2bf(v.z), f2bf(v.w)};
    *(ushort4*)(x_bf + i) = o;
    return;
  }
  i -= N0;
  if (i < N1) {
    const float4 v = *(const float4*)(w_in + i);
    ushort4 o = {f2bf(v.x), f2bf(v.y), f2bf(v.z), f2bf(v.w)};
    *(ushort4*)(w_in_bf + i) = o;
    return;
  }
  i -= N1;
  if (i < N2) {
    const float4 v = *(const float4*)(w_out + i);
    ushort4 o = {f2bf(v.x), f2bf(v.y), f2bf(v.z), f2bf(v.w)};
    *(ushort4*)(w_out_bf + i) = o;
    return;
  }
  i -= N2;
  if (i < N3) {
    const long row = i / 1536;
    ushort4 o = {0, 0, 0, 0};
    if (row < 160) {
      const float4 v = *(const float4*)(w_xp + i);
      o.x = f2bf(v.x); o.y = f2bf(v.y); o.z = f2bf(v.z); o.w = f2bf(v.w);
    }
    *(ushort4*)(w_xp_bf + i) = o;
    return;
  }
  i -= N3;
  if (i < N4) {
    const int col = (int)(i & 63);
    const long row = i >> 6;
    ushort4 o = {0, 0, 0, 0};
    if (col < 48) {
      const float4 v = *(const float4*)(w_dt + row * 48 + col);
      o.x = f2bf(v.x); o.y = f2bf(v.y); o.z = f2bf(v.z); o.w = f2bf(v.w);
    }
    *(ushort4*)(w_dt_bf + i) = o;
  }
}

// ---------------------------------------------------------------------------
// Depthwise conv (k=3, pad=1) + bias + SiLU, bf16 in/out. 8ch x 8 rows.
// ---------------------------------------------------------------------------
__global__ __launch_bounds__(256) void conv_silu_kernel(
    const ushort* __restrict__ xz, const float* __restrict__ cw,
    const float* __restrict__ cb, ushort* __restrict__ u_bf) {
  const int nd8 = D_INNER / 8;  // 192
  const int idx = blockIdx.x * 256 + threadIdx.x;
  const int d8 = idx % nd8;
  const int lg = (idx / nd8) % (L_SEQ / 8);
  const int b = idx / (nd8 * (L_SEQ / 8));
  const int d = d8 * 8;
  const int l0 = lg * 8;

  float w0[8], w1[8], w2[8], bs[8];
#pragma unroll
  for (int j = 0; j < 8; ++j) {
    w0[j] = cw[(d + j) * 3 + 0];
    w1[j] = cw[(d + j) * 3 + 1];
    w2[j] = cw[(d + j) * 3 + 2];
    bs[j] = cb[d + j];
  }
  const ushort* base = xz + ((size_t)b * L_SEQ) * 3072 + d;
  const ushort8_t zv = {0, 0, 0, 0, 0, 0, 0, 0};
  ushort8_t prev = (l0 > 0) ? *(const ushort8_t*)(base + (size_t)(l0 - 1) * 3072) : zv;
  ushort8_t curv = *(const ushort8_t*)(base + (size_t)l0 * 3072);
#pragma unroll
  for (int i = 0; i < 8; ++i) {
    const int l = l0 + i;
    const ushort8_t nxt =
        (l + 1 < L_SEQ) ? *(const ushort8_t*)(base + (size_t)(l + 1) * 3072) : zv;
    ushort8_t o;
#pragma unroll
    for (int j = 0; j < 8; ++j) {
      const float a = bs[j] + bf2f(prev[j]) * w0[j] + bf2f(curv[j]) * w1[j] +
                      bf2f(nxt[j]) * w2[j];
      o[j] = f2bf(a / (1.f + __expf(-a)));
    }
    *(ushort8_t*)(u_bf + ((size_t)b * L_SEQ + l) * D_INNER + d) = o;
    prev = curv;
    curv = nxt;
  }
}

// ---------------------------------------------------------------------------
// K1: local scan. ZERO LDS, zero barriers. Block = 4 independent waves; wave
// = one (k,b,dgB,chunk of 32). Lane = channel; 16 states in-lane.
// delta/u: coalesced per-step global u16 loads. B/C: f32 broadcast loads.
// ---------------------------------------------------------------------------
__global__ __launch_bounds__(256) void scan_local_kernel(
    const ushort* __restrict__ u_bf, const float* __restrict__ bcf,
    const ushort* __restrict__ delta_bf, const float* __restrict__ A_logs,
    const float* __restrict__ Ds, ushort* __restrict__ y,
    float* __restrict__ hfin, float* __restrict__ Tsum) {
  const int tid = threadIdx.x;
  const int wid = tid >> 6;
  const int lane = tid & 63;
  const int bid = blockIdx.x;
  const int chg = bid & (NCH / 4 - 1);
  const int rest = bid / (NCH / 4);
  const int dgB = rest % NDG;
  const int kb = rest / NDG;
  const int b = kb & 1;
  const int k = kb >> 1;
  const int ch = chg * 4 + wid;
  const int d = dgB * 64 + lane;
  const int row = k * D_INNER + d;

  float An[16];
#pragma unroll
  for (int q = 0; q < 4; ++q) {
    const float4 a = *(const float4*)(A_logs + (size_t)row * D_STATE + q * 4);
    An[q * 4 + 0] = -__expf(a.x) * LOG2E;
    An[q * 4 + 1] = -__expf(a.y) * LOG2E;
    An[q * 4 + 2] = -__expf(a.z) * LOG2E;
    An[q * 4 + 3] = -__expf(a.w) * LOG2E;
  }
  const float Dk = Ds[row];

  const int lstart = k ? (L_SEQ - 1 - ch * CH) : ch * CH;
  const ptrdiff_t dstr = k ? -(ptrdiff_t)D_INNER : (ptrdiff_t)D_INNER;
  const ptrdiff_t bstr = k ? -32 : 32;
  const ushort* dp =
      delta_bf + ((size_t)(k * B_SZ + b) * L_SEQ + lstart) * D_INNER + d;
  const ushort* up = u_bf + ((size_t)b * L_SEQ + lstart) * D_INNER + d;
  const float* bcp =
      bcf + ((size_t)k * MTOT + (size_t)b * L_SEQ + lstart) * 32;
  ushort* yp = y + ((size_t)(k * B_SZ + b) * L_SEQ + lstart) * D_INNER + d;

  float h[16] = {};
  float S = 0.f;

#pragma unroll 4
  for (int s = 0; s < CH; ++s) {
    const float dlt = bf2f(*dp);
    const float uu = bf2f(*up);
    S += dlt;
    const float du = dlt * uu;
    const float4 B0 = *(const float4*)(bcp + 0);
    const float4 B1 = *(const float4*)(bcp + 4);
    const float4 B2 = *(const float4*)(bcp + 8);
    const float4 B3 = *(const float4*)(bcp + 12);
    const float4 C0 = *(const float4*)(bcp + 16);
    const float4 C1 = *(const float4*)(bcp + 20);
    const float4 C2 = *(const float4*)(bcp + 24);
    const float4 C3 = *(const float4*)(bcp + 28);
    float yt = 0.f;
    h[0] = h[0] * ex2(dlt * An[0]) + du * B0.x;  yt += h[0] * C0.x;
    h[1] = h[1] * ex2(dlt * An[1]) + du * B0.y;  yt += h[1] * C0.y;
    h[2] = h[2] * ex2(dlt * An[2]) + du * B0.z;  yt += h[2] * C0.z;
    h[3] = h[3] * ex2(dlt * An[3]) + du * B0.w;  yt += h[3] * C0.w;
    h[4] = h[4] * ex2(dlt * An[4]) + du * B1.x;  yt += h[4] * C1.x;
    h[5] = h[5] * ex2(dlt * An[5]) + du * B1.y;  yt += h[5] * C1.y;
    h[6] = h[6] * ex2(dlt * An[6]) + du * B1.z;  yt += h[6] * C1.z;
    h[7] = h[7] * ex2(dlt * An[7]) + du * B1.w;  yt += h[7] * C1.w;
    h[8] = h[8] * ex2(dlt * An[8]) + du * B2.x;  yt += h[8] * C2.x;
    h[9] = h[9] * ex2(dlt * An[9]) + du * B2.y;  yt += h[9] * C2.y;
    h[10] = h[10] * ex2(dlt * An[10]) + du * B2.z; yt += h[10] * C2.z;
    h[11] = h[11] * ex2(dlt * An[11]) + du * B2.w; yt += h[11] * C2.w;
    h[12] = h[12] * ex2(dlt * An[12]) + du * B3.x; yt += h[12] * C3.x;
    h[13] = h[13] * ex2(dlt * An[13]) + du * B3.y; yt += h[13] * C3.y;
    h[14] = h[14] * ex2(dlt * An[14]) + du * B3.z; yt += h[14] * C3.z;
    h[15] = h[15] * ex2(dlt * An[15]) + du * B3.w; yt += h[15] * C3.w;
    *yp = f2bf(yt + uu * Dk);
    dp += dstr;
    up += dstr;
    yp += dstr;
    bcp += bstr;
  }

  const size_t cidxB = ((size_t)(k * B_SZ + b) * NCH + ch) * NDG + dgB;
#pragma unroll
  for (int q = 0; q < 4; ++q)
    *(float4*)(hfin + cidxB * 1024 + lane * 16 + q * 4) =
        make_float4(h[q * 4], h[q * 4 + 1], h[q * 4 + 2], h[q * 4 + 3]);
  Tsum[cidxB * 64 + lane] = S;
}

// ---------------------------------------------------------------------------
// K2: stitch. Block = (k,b,dgB). Thread = (dl = tid>>2, nq = tid&3).
// ---------------------------------------------------------------------------
__global__ __launch_bounds__(256) void scan_stitch_kernel(
    const float* __restrict__ hfin, const float* __restrict__ Tsum,
    const float* __restrict__ A_logs, float* __restrict__ hin) {
  const int tid = threadIdx.x;
  const int dl = tid >> 2;
  const int nq = tid & 3;
  const int bid = blockIdx.x;
  const int dgB = bid % NDG;
  const int b = (bid / NDG) & 1;
  const int k = bid / (NDG * 2);
  const int row = k * D_INNER + dgB * 64 + dl;
  const float4 alv = *(const float4*)(A_logs + (size_t)row * D_STATE + nq * 4);
  const float An0 = -__expf(alv.x) * LOG2E, An1 = -__expf(alv.y) * LOG2E;
  const float An2 = -__expf(alv.z) * LOG2E, An3 = -__expf(alv.w) * LOG2E;
  float c0 = 0.f, c1 = 0.f, c2 = 0.f, c3 = 0.f;
  for (int ch = 0; ch < NCH; ++ch) {
    const size_t cidxB = ((size_t)(k * B_SZ + b) * NCH + ch) * NDG + dgB;
    const size_t off = cidxB * 1024 + dl * 16 + nq * 4;
    *(float4*)(hin + off) = make_float4(c0, c1, c2, c3);
    const float T = Tsum[cidxB * 64 + dl];
    const float4 hf = *(const float4*)(hfin + off);
    c0 = c0 * ex2(An0 * T) + hf.x;
    c1 = c1 * ex2(An1 * T) + hf.y;
    c2 = c2 * ex2(An2 * T) + hf.z;
    c3 = c3 * ex2(An3 * T) + hf.w;
  }
}

// ---------------------------------------------------------------------------
// K3: fused fixup (both directions) + gate -> yg bf16. Tile = 64 rows, but
// chunks are 32: each wave (16 rows) uses its own chunk's carry + chunk-local
// delta cumsum (quarter-parity init). delta via gload; C f32 direct copies.
// ---------------------------------------------------------------------------
__global__ __launch_bounds__(256) void fixup_gate_kernel(
    const float* __restrict__ bcf, const ushort* __restrict__ delta_bf,
    const float* __restrict__ A_logs, const float* __restrict__ hin,
    const ushort* __restrict__ y, const ushort* __restrict__ xz_bf,
    ushort* __restrict__ yg) {
  __shared__ ushort sd0[64][64], sd1[64][64];  // bf16 delta tiles
  __shared__ float sC0f[64][16], sC1f[64][16]; // f32 C tiles
  __shared__ float sQF[64][4], sQB[64][4];
  const int tid = threadIdx.x;
  const int wid = tid >> 6;
  const int lane = tid & 63;
  const int tq = wid;
  const int dl = lane;
  const int bid = blockIdx.x;
  const int chf = bid & 31;        // 64-row tile index
  const int rest = bid >> 5;
  const int dgB = rest % NDG;
  const int b = rest / NDG;
  const int d0 = dgB * 64;
  const int d = d0 + dl;
  const int lbase = chf * 64;

  float AnF[16], AnB[16], hF[16], hB[16];
#pragma unroll
  for (int q = 0; q < 4; ++q) {
    const float4 af = *(const float4*)(A_logs + (size_t)d * D_STATE + q * 4);
    AnF[q * 4 + 0] = -__expf(af.x) * LOG2E;
    AnF[q * 4 + 1] = -__expf(af.y) * LOG2E;
    AnF[q * 4 + 2] = -__expf(af.z) * LOG2E;
    AnF[q * 4 + 3] = -__expf(af.w) * LOG2E;
    const float4 ab =
        *(const float4*)(A_logs + (size_t)(D_INNER + d) * D_STATE + q * 4);
    AnB[q * 4 + 0] = -__expf(ab.x) * LOG2E;
    AnB[q * 4 + 1] = -__expf(ab.y) * LOG2E;
    AnB[q * 4 + 2] = -__expf(ab.z) * LOG2E;
    AnB[q * 4 + 3] = -__expf(ab.w) * LOG2E;
  }
  // per-wave chunk indices (chunks of 32 rows)
  const int chF = chf * 2 + (tq >> 1);
  const int chB = NCH - 1 - chf * 2 - (tq >> 1);
  const size_t cF = ((size_t)(0 * B_SZ + b) * NCH + chF) * NDG + dgB;
  const size_t cB = ((size_t)(1 * B_SZ + b) * NCH + chB) * NDG + dgB;
#pragma unroll
  for (int q = 0; q < 4; ++q) {
    const float4 hv = *(const float4*)(hin + cF * 1024 + dl * 16 + q * 4);
    hF[q * 4 + 0] = hv.x; hF[q * 4 + 1] = hv.y;
    hF[q * 4 + 2] = hv.z; hF[q * 4 + 3] = hv.w;
    const float4 hw = *(const float4*)(hin + cB * 1024 + dl * 16 + q * 4);
    hB[q * 4 + 0] = hw.x; hB[q * 4 + 1] = hw.y;
    hB[q * 4 + 2] = hw.z; hB[q * 4 + 3] = hw.w;
  }

  const ushort* d0p =
      delta_bf + ((size_t)(0 * B_SZ + b) * L_SEQ + lbase) * D_INNER + d0;
  const ushort* d1p =
      delta_bf + ((size_t)(1 * B_SZ + b) * L_SEQ + lbase) * D_INNER + d0;
  // stage delta tiles: wave-sliced gloads (slice = (i*4+wid)*1024B = 8 rows)
  {
    const int rd = lane >> 3, seg = lane & 7;
#pragma unroll
    for (int i = 0; i < 2; ++i) {
      const int sl = i * 4 + wid;
      const int r = sl * 8 + rd;
      const size_t off = (size_t)r * D_INNER + seg * 8;
      gload_lds16(d0p + off, &sd0[0][0] + sl * 512);
      gload_lds16(d1p + off, &sd1[0][0] + sl * 512);
    }
  }
  // stage C tiles (f32 direct copies)
  {
    const float* bc0 = bcf + (size_t)b * L_SEQ * 32;
    const float* bc1 = bcf + (size_t)MTOT * 32 + (size_t)b * L_SEQ * 32;
    const int r = tid >> 2;
    const int q = tid & 3;
    *(float4*)&sC0f[r][q * 4] =
        *(const float4*)(bc0 + (size_t)(lbase + r) * 32 + 16 + q * 4);
    *(float4*)&sC1f[r][q * 4] =
        *(const float4*)(bc1 + (size_t)(lbase + r) * 32 + 16 + q * 4);
  }
  __syncthreads();
  float qf = 0.f, qb = 0.f;
#pragma unroll
  for (int i = 0; i < 16; ++i) {
    qf += bf2f(sd0[tq * 16 + i][dl]);
    qb += bf2f(sd1[tq * 16 + i][dl]);
  }
  sQF[dl][tq] = qf;
  sQB[dl][tq] = qb;
  __syncthreads();
  // chunk-local prefix: chunks are quarter-pairs {0,1} and {2,3}
  float SF = (tq & 1) ? sQF[dl][tq - 1] : 0.f;
  float SB = (tq & 1) ? 0.f : sQB[dl][tq + 1];

  const ushort* y0p = y + ((size_t)(0 * B_SZ + b) * L_SEQ) * D_INNER;
  const ushort* y1p = y + ((size_t)(1 * B_SZ + b) * L_SEQ) * D_INNER;
  float yacc[16];
#pragma unroll
  for (int i = 0; i < 16; ++i) {
    const int t = tq * 16 + i;
    SF += bf2f(sd0[t][dl]);
    const float4 C0 = *(const float4*)&sC0f[t][0];
    const float4 C1 = *(const float4*)&sC0f[t][4];
    const float4 C2 = *(const float4*)&sC0f[t][8];
    const float4 C3 = *(const float4*)&sC0f[t][12];
    float wf;
    wf  = C0.x * (ex2(AnF[0] * SF) * hF[0]);
    wf += C0.y * (ex2(AnF[1] * SF) * hF[1]);
    wf += C0.z * (ex2(AnF[2] * SF) * hF[2]);
    wf += C0.w * (ex2(AnF[3] * SF) * hF[3]);
    wf += C1.x * (ex2(AnF[4] * SF) * hF[4]);
    wf += C1.y * (ex2(AnF[5] * SF) * hF[5]);
    wf += C1.z * (ex2(AnF[6] * SF) * hF[6]);
    wf += C1.w * (ex2(AnF[7] * SF) * hF[7]);
    wf += C2.x * (ex2(AnF[8] * SF) * hF[8]);
    wf += C2.y * (ex2(AnF[9] * SF) * hF[9]);
    wf += C2.z * (ex2(AnF[10] * SF) * hF[10]);
    wf += C2.w * (ex2(AnF[11] * SF) * hF[11]);
    wf += C3.x * (ex2(AnF[12] * SF) * hF[12]);
    wf += C3.y * (ex2(AnF[13] * SF) * hF[13]);
    wf += C3.z * (ex2(AnF[14] * SF) * hF[14]);
    wf += C3.w * (ex2(AnF[15] * SF) * hF[15]);
    yacc[i] = bf2f(y0p[(size_t)(lbase + t) * D_INNER + d]) + wf;
  }
#pragma unroll
  for (int i = 15; i >= 0; --i) {
    const int t = tq * 16 + i;
    SB += bf2f(sd1[t][dl]);
    const float4 C0 = *(const float4*)&sC1f[t][0];
    const float4 C1 = *(const float4*)&sC1f[t][4];
    const float4 C2 = *(const float4*)&sC1f[t][8];
    const float4 C3 = *(const float4*)&sC1f[t][12];
    float wb;
    wb  = C0.x * (ex2(AnB[0] * SB) * hB[0]);
    wb += C0.y * (ex2(AnB[1] * SB) * hB[1]);
    wb += C0.z * (ex2(AnB[2] * SB) * hB[2]);
    wb += C0.w * (ex2(AnB[3] * SB) * hB[3]);
    wb += C1.x * (ex2(AnB[4] * SB) * hB[4]);
    wb += C1.y * (ex2(AnB[5] * SB) * hB[5]);
    wb += C1.z * (ex2(AnB[6] * SB) * hB[6]);
    wb += C1.w * (ex2(AnB[7] * SB) * hB[7]);
    wb += C2.x * (ex2(AnB[8] * SB) * hB[8]);
    wb += C2.y * (ex2(AnB[9] * SB) * hB[9]);
    wb += C2.z * (ex2(AnB[10] * SB) * hB[10]);
    wb += C2.w * (ex2(AnB[11] * SB) * hB[11]);
    wb += C3.x * (ex2(AnB[12] * SB) * hB[12]);
    wb += C3.y * (ex2(AnB[13] * SB) * hB[13]);
    wb += C3.z * (ex2(AnB[14] * SB) * hB[14]);
    wb += C3.w * (ex2(AnB[15] * SB) * hB[15]);
    yacc[i] += bf2f(y1p[(size_t)(lbase + t) * D_INNER + d]) + wb;
  }
#pragma unroll
  for (int i = 0; i < 16; ++i) {
    const int l = lbase + tq * 16 + i;
    const float z = bf2f(xz_bf[((size_t)b * L_SEQ + l) * 3072 + 1536 + d]);
    yg[((size_t)b * L_SEQ + l) * D_INNER + d] = f2bf(yacc[i] * z);
  }
}

// ---------------------------------------------------------------------------
extern "C" void kernel_launch(void* const* d_in, const int* in_sizes, int n_in,
                              void* d_out, int out_size, void* d_ws,
                              size_t ws_size, hipStream_t stream) {
  const float* x          = (const float*)d_in[0];
  const float* in_proj_w  = (const float*)d_in[1];
  const float* conv_w     = (const float*)d_in[2];
  const float* conv_b     = (const float*)d_in[3];
  const float* x_proj_w   = (const float*)d_in[4];
  const float* dt_proj_w  = (const float*)d_in[5];
  const float* dt_proj_b  = (const float*)d_in[6];
  const float* A_logs     = (const float*)d_in[7];
  const float* Ds         = (const float*)d_in[8];
  const float* out_proj_w = (const float*)d_in[9];
  float* out = (float*)d_out;

  const int M = MTOT;
  const size_t NST = (size_t)2 * B_SZ * NCH * NDG;  // 6144

  float* ws    = (float*)d_ws;
  float* hfin  = ws;                          // NST*1024
  float* hin   = hfin + NST * 1024;           // NST*1024
  float* Tsum  = hin + NST * 1024;            // NST*64
  float* bcf   = Tsum + NST * 64;             // 2*M*32 f32
  ushort* x_bf     = (ushort*)(bcf + (size_t)2 * M * 32);
  ushort* w_in_bf  = x_bf + (size_t)M * 768;
  ushort* w_out_bf = w_in_bf + (size_t)3072 * 768;
  ushort* w_xp_bf  = w_out_bf + (size_t)768 * 1536;
  ushort* w_dt_bf  = w_xp_bf + (size_t)256 * 1536;
  ushort* xz_bf    = w_dt_bf + (size_t)2 * 1536 * 64;
  ushort* u_bf     = xz_bf + (size_t)M * 3072;
  ushort* delta_bf = u_bf + (size_t)M * 1536;
  ushort* dtin     = delta_bf + (size_t)2 * M * 1536;
  ushort* y_bf     = dtin + (size_t)2 * M * 64;
  ushort* yg_bf    = y_bf + (size_t)2 * M * 1536;

  dim3 blk(256);

  // 0. conversions (one kernel)
  {
    const long TOT = 3145728L + 2359296 + 1179648 + 393216 + 196608;
    cvt_all_kernel<<<dim3((TOT / 4 + 255) / 256), blk, 0, stream>>>(
        x, in_proj_w, out_proj_w, x_proj_w, dt_proj_w, x_bf, w_in_bf, w_out_bf,
        w_xp_bf, w_dt_bf);
  }

  // 1. xz = x @ in_proj_w^T  -> bf16
  gemm_k<128, 128, 0, 1, 0><<<dim3(3072 / 128, M / 128), blk, 0, stream>>>(
      x_bf, 768, w_in_bf, 768, nullptr, xz_bf, 3072, 3072, 768, nullptr,
      nullptr);

  // 2. u = silu(conv(x_conv)+bias) -> bf16
  conv_silu_kernel<<<dim3(B_SZ * (L_SEQ / 8) * (D_INNER / 8) / 256), blk, 0,
                     stream>>>(xz_bf, conv_w, conv_b, u_bf);

  // 3. dtin + bcf(f32) = u @ x_proj_w^T epilogue
  gemm_k<32, 64, 0, 0, 1><<<dim3(3, M / 32), blk, 0, stream>>>(
      u_bf, 1536, w_xp_bf, 1536, nullptr, nullptr, 1, 0, 1536, dtin, bcf);

  // 4. delta = softplus(dtin @ dtw^T + dtb) -> bf16 (both k, one dispatch)
  gemm_dt_k<<<dim3(1536 / 128, M / 64, 2), blk, 0, stream>>>(
      dtin, w_dt_bf, dt_proj_b, delta_bf);

  // 5. scan
  scan_local_kernel<<<dim3(2 * B_SZ * NDG * (NCH / 4)), blk, 0, stream>>>(
      u_bf, bcf, delta_bf, A_logs, Ds, y_bf, hfin, Tsum);
  scan_stitch_kernel<<<dim3(2 * B_SZ * NDG), blk, 0, stream>>>(hfin, Tsum,
                                                               A_logs, hin);
  // 6. fused fixup(both dirs) + gate -> yg bf16
  fixup_gate_kernel<<<dim3(B_SZ * NDG * (L_SEQ / 64)), blk, 0, stream>>>(
      bcf, delta_bf, A_logs, hin, y_bf, xz_bf, yg_bf);

  // 7. out = yg @ out_proj_w^T -> fp32
  gemm_k<128, 128, 0, 0, 0><<<dim3(768 / 128, M / 128), blk, 0, stream>>>(
      yg_bf, 1536, w_out_bf, 1536, nullptr, out, 768, 768, 1536, nullptr,
      nullptr);
}

// Round 16
// 247.649 us; speedup vs baseline: 1.0316x; 1.0316x over previous
//
#include <hip/hip_runtime.h>
#include <math.h>

#define D_MODEL 768
#define D_STATE 16
#define D_INNER 1536
#define DT_RANK 48
#define B_SZ    2
#define L_SEQ   2048
#define CH      32             // scan chunk length
#define NCH     (L_SEQ / CH)   // 64 chunks
#define NDG     24             // d-groups of 64 channels (state layout)
#define MTOT    (B_SZ * L_SEQ) // 4096
#define LOG2E   1.4426950408889634f
#define LN2     0.6931471805599453f

typedef __bf16 bf16x8 __attribute__((ext_vector_type(8)));
typedef float f32x4 __attribute__((ext_vector_type(4)));
typedef ushort ushort8_t __attribute__((ext_vector_type(8)));

__device__ __forceinline__ float ex2(float x) {
  return __builtin_amdgcn_exp2f(x);  // v_exp_f32: D = 2^S0
}

__device__ __forceinline__ ushort f2bf(float f) {
  unsigned int u = __float_as_uint(f);
  unsigned int r = (u + 0x7fff + ((u >> 16) & 1)) >> 16;
  return (ushort)r;
}
__device__ __forceinline__ float bf2f(ushort u) {
  return __uint_as_float(((unsigned int)u) << 16);
}

__device__ __forceinline__ void gload_lds16(const ushort* g, ushort* l) {
  __builtin_amdgcn_global_load_lds(
      (__attribute__((address_space(1))) void*)(void*)(g),
      (__attribute__((address_space(3))) void*)(void*)(l), 16, 0, 0);
}

// Force a pointer (already uniform in value) to be compiler-provably uniform
// so loads through it become s_load (scalar pipe).
__device__ __forceinline__ const float* uniform_ptr(const float* p) {
  unsigned long long v = (unsigned long long)p;
  unsigned int lo = __builtin_amdgcn_readfirstlane((unsigned int)v);
  unsigned int hi = __builtin_amdgcn_readfirstlane((unsigned int)(v >> 32));
  return (const float*)(((unsigned long long)hi << 32) | lo);
}

// fast softplus: ln(1+e^x) = ln2 * log2(1 + 2^(x*log2e)); guard large x
__device__ __forceinline__ float softplus_fast(float x) {
  return (x > 20.f) ? x : LN2 * __log2f(1.f + ex2(x * LOG2E));
}

// ---------------------------------------------------------------------------
// bf16 MFMA GEMM body, double-buffered 2-phase K-loop.
// C[M,N] = A[M,K] * B[N,K]^T (+bias, +softplus). OBF: bf16 C. DTOUT: emit
// dtin bf16 (cols 0..47 -> k0, 80..127 -> k1, pad 64) + bcbuf FP32
// ([2][M][32]: B=cols 48..63/128..143, C=cols 64..79/144..159).
// ---------------------------------------------------------------------------
template <int BM, int BN, int ACT, int OBF, int DTOUT>
__device__ __forceinline__ void gemm_body(
    const ushort* __restrict__ A, int lda, const ushort* __restrict__ B,
    int ldb, const float* __restrict__ bias, void* __restrict__ Cp, int ldc,
    int Nreal, int K, int bxi, int byi, ushort* __restrict__ dtin,
    float* __restrict__ bcp) {
  __shared__ ushort As[2][BM][32];
  __shared__ ushort Bs[2][BN][32];
  constexpr int WM = BM / 2, WN = BN / 2;
  constexpr int FM = WM / 16, FN = WN / 16;
  const int tid = threadIdx.x;
  const int lane = tid & 63;
  const int w = tid >> 6;
  const int wr = w >> 1, wc = w & 1;
  const int bm = byi * BM, bn = bxi * BN;
  const int lrow = lane >> 2;
  const int lchunk = lane & 3;
  const int fr = lane & 15;
  const int k8 = (lane >> 4) * 8;

  f32x4 acc[FM][FN] = {};

  auto stage = [&](int buf, int k0) {
    if constexpr (BM >= 64) {
#pragma unroll
      for (int g = 0; g < BM / 64; ++g) {
        const int rb = w * (BM / 4) + g * 16;
        gload_lds16(A + (size_t)(bm + rb + lrow) * lda + k0 + lchunk * 8,
                    &As[buf][rb][0]);
      }
    } else {  // BM == 32
      if (w < 2)
        gload_lds16(A + (size_t)(bm + w * 16 + lrow) * lda + k0 + lchunk * 8,
                    &As[buf][w * 16][0]);
    }
#pragma unroll
    for (int g = 0; g < BN / 64; ++g) {
      const int rb = w * (BN / 4) + g * 16;
      gload_lds16(B + (size_t)(bn + rb + lrow) * ldb + k0 + lchunk * 8,
                  &Bs[buf][rb][0]);
    }
  };

  stage(0, 0);
  __syncthreads();
  int cur = 0;
  for (int k0 = 0; k0 < K; k0 += 32) {
    if (k0 + 32 < K) stage(cur ^ 1, k0 + 32);
    bf16x8 af[FM], bfr[FN];
#pragma unroll
    for (int m = 0; m < FM; ++m)
      af[m] =
          *reinterpret_cast<const bf16x8*>(&As[cur][wr * WM + m * 16 + fr][k8]);
#pragma unroll
    for (int n = 0; n < FN; ++n)
      bfr[n] =
          *reinterpret_cast<const bf16x8*>(&Bs[cur][wc * WN + n * 16 + fr][k8]);
#pragma unroll
    for (int m = 0; m < FM; ++m)
#pragma unroll
      for (int n = 0; n < FN; ++n)
        acc[m][n] = __builtin_amdgcn_mfma_f32_16x16x32_bf16(af[m], bfr[n],
                                                            acc[m][n], 0, 0, 0);
    __syncthreads();
    cur ^= 1;
  }

  const int row4 = (lane >> 4) * 4;
#pragma unroll
  for (int m = 0; m < FM; ++m) {
#pragma unroll
    for (int n = 0; n < FN; ++n) {
      const int gn = bn + wc * WN + n * 16 + fr;
      const int gm0 = bm + wr * WM + m * 16 + row4;
#pragma unroll
      for (int j = 0; j < 4; ++j) {
        const float v = acc[m][n][j];
        const int gm = gm0 + j;
        if (DTOUT) {
          if (gn < 64)
            dtin[(size_t)gm * 64 + gn] = (gn < 48) ? f2bf(v) : (ushort)0;
          else if (gn >= 80 && gn < 144)
            dtin[(size_t)MTOT * 64 + (size_t)gm * 64 + (gn - 80)] =
                (gn < 128) ? f2bf(v) : (ushort)0;
          if (gn >= 48 && gn < 80)
            bcp[(size_t)gm * 32 + (gn - 48)] = v;
          else if (gn >= 128 && gn < 160)
            bcp[(size_t)MTOT * 32 + (size_t)gm * 32 + (gn - 128)] = v;
        }
        if (gn < Nreal) {
          float vv = v + (bias ? bias[gn] : 0.f);
          if (ACT == 1) vv = softplus_fast(vv);
          if (OBF)
            ((ushort*)Cp)[(size_t)gm * ldc + gn] = f2bf(vv);
          else
            ((float*)Cp)[(size_t)gm * ldc + gn] = vv;
        }
      }
    }
  }
}

template <int BM, int BN, int ACT, int OBF, int DTOUT>
__global__ __launch_bounds__(256) void gemm_k(
    const ushort* __restrict__ A, int lda, const ushort* __restrict__ B,
    int ldb, const float* __restrict__ bias, void* __restrict__ Cp, int ldc,
    int Nreal, int K, ushort* __restrict__ dtin, float* __restrict__ bcp) {
  gemm_body<BM, BN, ACT, OBF, DTOUT>(A, lda, B, ldb, bias, Cp, ldc, Nreal, K,
                                     blockIdx.x, blockIdx.y, dtin, bcp);
}

// dt_proj both directions in one dispatch (blockIdx.z = k); 64x128 tile
__global__ __launch_bounds__(256) void gemm_dt_k(
    const ushort* __restrict__ dtin, const ushort* __restrict__ w_dt,
    const float* __restrict__ dtb, ushort* __restrict__ delta) {
  const int k = blockIdx.z;
  gemm_body<64, 128, 1, 1, 0>(
      dtin + (size_t)k * MTOT * 64, 64, w_dt + (size_t)k * D_INNER * 64, 64,
      dtb + k * D_INNER, delta + (size_t)k * MTOT * D_INNER, D_INNER, D_INNER,
      64, blockIdx.x, blockIdx.y, nullptr, nullptr);
}

// ---------------------------------------------------------------------------
// One-shot fp32->bf16 conversion of x + all weights (with padding).
// ---------------------------------------------------------------------------
__global__ __launch_bounds__(256) void cvt_all_kernel(
    const float* __restrict__ x, const float* __restrict__ w_in,
    const float* __restrict__ w_out, const float* __restrict__ w_xp,
    const float* __restrict__ w_dt, ushort* __restrict__ x_bf,
    ushort* __restrict__ w_in_bf, ushort* __restrict__ w_out_bf,
    ushort* __restrict__ w_xp_bf, ushort* __restrict__ w_dt_bf) {
  const long N0 = 3145728, N1 = 2359296, N2 = 1179648, N3 = 393216, N4 = 196608;
  long i = ((long)blockIdx.x * 256 + threadIdx.x) * 4;
  if (i < N0) {
    const float4 v = *(const float4*)(x + i);
    ushort4 o = {f2bf(v.x), f2bf(v.y), f2bf(v.z), f2bf(v.w)};
    *(ushort4*)(x_bf + i) = o;
    return;
  }
  i -= N0;
  if (i < N1) {
    const float4 v = *(const float4*)(w_in + i);
    ushort4 o = {f2bf(v.x), f2bf(v.y), f2bf(v.z), f2bf(v.w)};
    *(ushort4*)(w_in_bf + i) = o;
    return;
  }
  i -= N1;
  if (i < N2) {
    const float4 v = *(const float4*)(w_out + i);
    ushort4 o = {f2bf(v.x), f2bf(v.y), f2bf(v.z), f2bf(v.w)};
    *(ushort4*)(w_out_bf + i) = o;
    return;
  }
  i -= N2;
  if (i < N3) {
    const long row = i / 1536;
    ushort4 o = {0, 0, 0, 0};
    if (row < 160) {
      const float4 v = *(const float4*)(w_xp + i);
      o.x = f2bf(v.x); o.y = f2bf(v.y); o.z = f2bf(v.z); o.w = f2bf(v.w);
    }
    *(ushort4*)(w_xp_bf + i) = o;
    return;
  }
  i -= N3;
  if (i < N4) {
    const int col = (int)(i & 63);
    const long row = i >> 6;
    ushort4 o = {0, 0, 0, 0};
    if (col < 48) {
      const float4 v = *(const float4*)(w_dt + row * 48 + col);
      o.x = f2bf(v.x); o.y = f2bf(v.y); o.z = f2bf(v.z); o.w = f2bf(v.w);
    }
    *(ushort4*)(w_dt_bf + i) = o;
  }
}

// ---------------------------------------------------------------------------
// Depthwise conv (k=3, pad=1) + bias + SiLU, bf16 in/out. 8ch x 8 rows.
// ---------------------------------------------------------------------------
__global__ __launch_bounds__(256) void conv_silu_kernel(
    const ushort* __restrict__ xz, const float* __restrict__ cw,
    const float* __restrict__ cb, ushort* __restrict__ u_bf) {
  const int nd8 = D_INNER / 8;  // 192
  const int idx = blockIdx.x * 256 + threadIdx.x;
  const int d8 = idx % nd8;
  const int lg = (idx / nd8) % (L_SEQ / 8);
  const int b = idx / (nd8 * (L_SEQ / 8));
  const int d = d8 * 8;
  const int l0 = lg * 8;

  float w0[8], w1[8], w2[8], bs[8];
#pragma unroll
  for (int j = 0; j < 8; ++j) {
    w0[j] = cw[(d + j) * 3 + 0];
    w1[j] = cw[(d + j) * 3 + 1];
    w2[j] = cw[(d + j) * 3 + 2];
    bs[j] = cb[d + j];
  }
  const ushort* base = xz + ((size_t)b * L_SEQ) * 3072 + d;
  const ushort8_t zv = {0, 0, 0, 0, 0, 0, 0, 0};
  ushort8_t prev = (l0 > 0) ? *(const ushort8_t*)(base + (size_t)(l0 - 1) * 3072) : zv;
  ushort8_t curv = *(const ushort8_t*)(base + (size_t)l0 * 3072);
#pragma unroll
  for (int i = 0; i < 8; ++i) {
    const int l = l0 + i;
    const ushort8_t nxt =
        (l + 1 < L_SEQ) ? *(const ushort8_t*)(base + (size_t)(l + 1) * 3072) : zv;
    ushort8_t o;
#pragma unroll
    for (int j = 0; j < 8; ++j) {
      const float a = bs[j] + bf2f(prev[j]) * w0[j] + bf2f(curv[j]) * w1[j] +
                      bf2f(nxt[j]) * w2[j];
      o[j] = f2bf(a / (1.f + __expf(-a)));
    }
    *(ushort8_t*)(u_bf + ((size_t)b * L_SEQ + l) * D_INNER + d) = o;
    prev = curv;
    curv = nxt;
  }
}

// ---------------------------------------------------------------------------
// K1: local scan. ZERO LDS. Block = 256 threads = 256 CHANNELS, all 4 waves
// share one chunk -> B/C pointer is block-uniform -> scalar s_load pipe.
// Lane-private 16 states; delta/u coalesced u16 loads; 3 VMEM/step total.
// ---------------------------------------------------------------------------
__global__ __launch_bounds__(256) void scan_local_kernel(
    const ushort* __restrict__ u_bf, const float* __restrict__ bcf,
    const ushort* __restrict__ delta_bf, const float* __restrict__ A_logs,
    const float* __restrict__ Ds, ushort* __restrict__ y,
    float* __restrict__ hfin, float* __restrict__ Tsum) {
  const int tid = threadIdx.x;
  const int bid = blockIdx.x;
  const int ch = bid & (NCH - 1);   // 64 chunks
  const int rest = bid >> 6;
  const int dgB6 = rest % 6;        // 256-channel group
  const int kb = rest / 6;
  const int b = kb & 1;
  const int k = kb >> 1;
  const int d = dgB6 * 256 + tid;
  const int row = k * D_INNER + d;

  float An[16];
#pragma unroll
  for (int q = 0; q < 4; ++q) {
    const float4 a = *(const float4*)(A_logs + (size_t)row * D_STATE + q * 4);
    An[q * 4 + 0] = -__expf(a.x) * LOG2E;
    An[q * 4 + 1] = -__expf(a.y) * LOG2E;
    An[q * 4 + 2] = -__expf(a.z) * LOG2E;
    An[q * 4 + 3] = -__expf(a.w) * LOG2E;
  }
  const float Dk = Ds[row];

  const int lstart = k ? (L_SEQ - 1 - ch * CH) : ch * CH;
  const ptrdiff_t dstr = k ? -(ptrdiff_t)D_INNER : (ptrdiff_t)D_INNER;
  const ptrdiff_t bstr = k ? -32 : 32;
  const ushort* dp =
      delta_bf + ((size_t)(k * B_SZ + b) * L_SEQ + lstart) * D_INNER + d;
  const ushort* up = u_bf + ((size_t)b * L_SEQ + lstart) * D_INNER + d;
  ushort* yp = y + ((size_t)(k * B_SZ + b) * L_SEQ + lstart) * D_INNER + d;
  const float* bcp = uniform_ptr(
      bcf + ((size_t)k * MTOT + (size_t)b * L_SEQ + lstart) * 32);

  float h[16] = {};
  float S = 0.f;

#pragma unroll 2
  for (int s = 0; s < CH; ++s) {
    const float dlt = bf2f(*dp);
    const float uu = bf2f(*up);
    S += dlt;
    const float du = dlt * uu;
    float yt = 0.f;
#pragma unroll
    for (int j = 0; j < 16; ++j) {
      h[j] = h[j] * ex2(dlt * An[j]) + du * bcp[j];
      yt += h[j] * bcp[16 + j];
    }
    *yp = f2bf(yt + uu * Dk);
    dp += dstr;
    up += dstr;
    yp += dstr;
    bcp += bstr;
  }

  const int dg64 = dgB6 * 4 + (tid >> 6);  // 64-ch subgroup in [0,24)
  const int lane = tid & 63;
  const size_t cidxB = ((size_t)(k * B_SZ + b) * NCH + ch) * NDG + dg64;
#pragma unroll
  for (int q = 0; q < 4; ++q)
    *(float4*)(hfin + cidxB * 1024 + lane * 16 + q * 4) =
        make_float4(h[q * 4], h[q * 4 + 1], h[q * 4 + 2], h[q * 4 + 3]);
  Tsum[cidxB * 64 + lane] = S;
}

// ---------------------------------------------------------------------------
// K2: stitch. Block = (k,b,dgB). Thread = (dl = tid>>2, nq = tid&3).
// ---------------------------------------------------------------------------
__global__ __launch_bounds__(256) void scan_stitch_kernel(
    const float* __restrict__ hfin, const float* __restrict__ Tsum,
    const float* __restrict__ A_logs, float* __restrict__ hin) {
  const int tid = threadIdx.x;
  const int dl = tid >> 2;
  const int nq = tid & 3;
  const int bid = blockIdx.x;
  const int dgB = bid % NDG;
  const int b = (bid / NDG) & 1;
  const int k = bid / (NDG * 2);
  const int row = k * D_INNER + dgB * 64 + dl;
  const float4 alv = *(const float4*)(A_logs + (size_t)row * D_STATE + nq * 4);
  const float An0 = -__expf(alv.x) * LOG2E, An1 = -__expf(alv.y) * LOG2E;
  const float An2 = -__expf(alv.z) * LOG2E, An3 = -__expf(alv.w) * LOG2E;
  float c0 = 0.f, c1 = 0.f, c2 = 0.f, c3 = 0.f;
  for (int ch = 0; ch < NCH; ++ch) {
    const size_t cidxB = ((size_t)(k * B_SZ + b) * NCH + ch) * NDG + dgB;
    const size_t off = cidxB * 1024 + dl * 16 + nq * 4;
    *(float4*)(hin + off) = make_float4(c0, c1, c2, c3);
    const float T = Tsum[cidxB * 64 + dl];
    const float4 hf = *(const float4*)(hfin + off);
    c0 = c0 * ex2(An0 * T) + hf.x;
    c1 = c1 * ex2(An1 * T) + hf.y;
    c2 = c2 * ex2(An2 * T) + hf.z;
    c3 = c3 * ex2(An3 * T) + hf.w;
  }
}

// ---------------------------------------------------------------------------
// K3: fused fixup (both directions) + gate -> yg bf16. Tile = 64 rows, but
// chunks are 32: each wave (16 rows) uses its own chunk's carry + chunk-local
// delta cumsum (quarter-parity init). delta via gload; C f32 direct copies.
// ---------------------------------------------------------------------------
__global__ __launch_bounds__(256) void fixup_gate_kernel(
    const float* __restrict__ bcf, const ushort* __restrict__ delta_bf,
    const float* __restrict__ A_logs, const float* __restrict__ hin,
    const ushort* __restrict__ y, const ushort* __restrict__ xz_bf,
    ushort* __restrict__ yg) {
  __shared__ ushort sd0[64][64], sd1[64][64];  // bf16 delta tiles
  __shared__ float sC0f[64][16], sC1f[64][16]; // f32 C tiles
  __shared__ float sQF[64][4], sQB[64][4];
  const int tid = threadIdx.x;
  const int wid = tid >> 6;
  const int lane = tid & 63;
  const int tq = wid;
  const int dl = lane;
  const int bid = blockIdx.x;
  const int chf = bid & 31;        // 64-row tile index
  const int rest = bid >> 5;
  const int dgB = rest % NDG;
  const int b = rest / NDG;
  const int d0 = dgB * 64;
  const int d = d0 + dl;
  const int lbase = chf * 64;

  float AnF[16], AnB[16], hF[16], hB[16];
#pragma unroll
  for (int q = 0; q < 4; ++q) {
    const float4 af = *(const float4*)(A_logs + (size_t)d * D_STATE + q * 4);
    AnF[q * 4 + 0] = -__expf(af.x) * LOG2E;
    AnF[q * 4 + 1] = -__expf(af.y) * LOG2E;
    AnF[q * 4 + 2] = -__expf(af.z) * LOG2E;
    AnF[q * 4 + 3] = -__expf(af.w) * LOG2E;
    const float4 ab =
        *(const float4*)(A_logs + (size_t)(D_INNER + d) * D_STATE + q * 4);
    AnB[q * 4 + 0] = -__expf(ab.x) * LOG2E;
    AnB[q * 4 + 1] = -__expf(ab.y) * LOG2E;
    AnB[q * 4 + 2] = -__expf(ab.z) * LOG2E;
    AnB[q * 4 + 3] = -__expf(ab.w) * LOG2E;
  }
  // per-wave chunk indices (chunks of 32 rows)
  const int chF = chf * 2 + (tq >> 1);
  const int chB = NCH - 1 - chf * 2 - (tq >> 1);
  const size_t cF = ((size_t)(0 * B_SZ + b) * NCH + chF) * NDG + dgB;
  const size_t cB = ((size_t)(1 * B_SZ + b) * NCH + chB) * NDG + dgB;
#pragma unroll
  for (int q = 0; q < 4; ++q) {
    const float4 hv = *(const float4*)(hin + cF * 1024 + dl * 16 + q * 4);
    hF[q * 4 + 0] = hv.x; hF[q * 4 + 1] = hv.y;
    hF[q * 4 + 2] = hv.z; hF[q * 4 + 3] = hv.w;
    const float4 hw = *(const float4*)(hin + cB * 1024 + dl * 16 + q * 4);
    hB[q * 4 + 0] = hw.x; hB[q * 4 + 1] = hw.y;
    hB[q * 4 + 2] = hw.z; hB[q * 4 + 3] = hw.w;
  }

  const ushort* d0p =
      delta_bf + ((size_t)(0 * B_SZ + b) * L_SEQ + lbase) * D_INNER + d0;
  const ushort* d1p =
      delta_bf + ((size_t)(1 * B_SZ + b) * L_SEQ + lbase) * D_INNER + d0;
  // stage delta tiles: wave-sliced gloads (slice = (i*4+wid)*1024B = 8 rows)
  {
    const int rd = lane >> 3, seg = lane & 7;
#pragma unroll
    for (int i = 0; i < 2; ++i) {
      const int sl = i * 4 + wid;
      const int r = sl * 8 + rd;
      const size_t off = (size_t)r * D_INNER + seg * 8;
      gload_lds16(d0p + off, &sd0[0][0] + sl * 512);
      gload_lds16(d1p + off, &sd1[0][0] + sl * 512);
    }
  }
  // stage C tiles (f32 direct copies)
  {
    const float* bc0 = bcf + (size_t)b * L_SEQ * 32;
    const float* bc1 = bcf + (size_t)MTOT * 32 + (size_t)b * L_SEQ * 32;
    const int r = tid >> 2;
    const int q = tid & 3;
    *(float4*)&sC0f[r][q * 4] =
        *(const float4*)(bc0 + (size_t)(lbase + r) * 32 + 16 + q * 4);
    *(float4*)&sC1f[r][q * 4] =
        *(const float4*)(bc1 + (size_t)(lbase + r) * 32 + 16 + q * 4);
  }
  __syncthreads();
  float qf = 0.f, qb = 0.f;
#pragma unroll
  for (int i = 0; i < 16; ++i) {
    qf += bf2f(sd0[tq * 16 + i][dl]);
    qb += bf2f(sd1[tq * 16 + i][dl]);
  }
  sQF[dl][tq] = qf;
  sQB[dl][tq] = qb;
  __syncthreads();
  // chunk-local prefix: chunks are quarter-pairs {0,1} and {2,3}
  float SF = (tq & 1) ? sQF[dl][tq - 1] : 0.f;
  float SB = (tq & 1) ? 0.f : sQB[dl][tq + 1];

  const ushort* y0p = y + ((size_t)(0 * B_SZ + b) * L_SEQ) * D_INNER;
  const ushort* y1p = y + ((size_t)(1 * B_SZ + b) * L_SEQ) * D_INNER;
  float yacc[16];
#pragma unroll
  for (int i = 0; i < 16; ++i) {
    const int t = tq * 16 + i;
    SF += bf2f(sd0[t][dl]);
    const float4 C0 = *(const float4*)&sC0f[t][0];
    const float4 C1 = *(const float4*)&sC0f[t][4];
    const float4 C2 = *(const float4*)&sC0f[t][8];
    const float4 C3 = *(const float4*)&sC0f[t][12];
    float wf;
    wf  = C0.x * (ex2(AnF[0] * SF) * hF[0]);
    wf += C0.y * (ex2(AnF[1] * SF) * hF[1]);
    wf += C0.z * (ex2(AnF[2] * SF) * hF[2]);
    wf += C0.w * (ex2(AnF[3] * SF) * hF[3]);
    wf += C1.x * (ex2(AnF[4] * SF) * hF[4]);
    wf += C1.y * (ex2(AnF[5] * SF) * hF[5]);
    wf += C1.z * (ex2(AnF[6] * SF) * hF[6]);
    wf += C1.w * (ex2(AnF[7] * SF) * hF[7]);
    wf += C2.x * (ex2(AnF[8] * SF) * hF[8]);
    wf += C2.y * (ex2(AnF[9] * SF) * hF[9]);
    wf += C2.z * (ex2(AnF[10] * SF) * hF[10]);
    wf += C2.w * (ex2(AnF[11] * SF) * hF[11]);
    wf += C3.x * (ex2(AnF[12] * SF) * hF[12]);
    wf += C3.y * (ex2(AnF[13] * SF) * hF[13]);
    wf += C3.z * (ex2(AnF[14] * SF) * hF[14]);
    wf += C3.w * (ex2(AnF[15] * SF) * hF[15]);
    yacc[i] = bf2f(y0p[(size_t)(lbase + t) * D_INNER + d]) + wf;
  }
#pragma unroll
  for (int i = 15; i >= 0; --i) {
    const int t = tq * 16 + i;
    SB += bf2f(sd1[t][dl]);
    const float4 C0 = *(const float4*)&sC1f[t][0];
    const float4 C1 = *(const float4*)&sC1f[t][4];
    const float4 C2 = *(const float4*)&sC1f[t][8];
    const float4 C3 = *(const float4*)&sC1f[t][12];
    float wb;
    wb  = C0.x * (ex2(AnB[0] * SB) * hB[0]);
    wb += C0.y * (ex2(AnB[1] * SB) * hB[1]);
    wb += C0.z * (ex2(AnB[2] * SB) * hB[2]);
    wb += C0.w * (ex2(AnB[3] * SB) * hB[3]);
    wb += C1.x * (ex2(AnB[4] * SB) * hB[4]);
    wb += C1.y * (ex2(AnB[5] * SB) * hB[5]);
    wb += C1.z * (ex2(AnB[6] * SB) * hB[6]);
    wb += C1.w * (ex2(AnB[7] * SB) * hB[7]);
    wb += C2.x * (ex2(AnB[8] * SB) * hB[8]);
    wb += C2.y * (ex2(AnB[9] * SB) * hB[9]);
    wb += C2.z * (ex2(AnB[10] * SB) * hB[10]);
    wb += C2.w * (ex2(AnB[11] * SB) * hB[11]);
    wb += C3.x * (ex2(AnB[12] * SB) * hB[12]);
    wb += C3.y * (ex2(AnB[13] * SB) * hB[13]);
    wb += C3.z * (ex2(AnB[14] * SB) * hB[14]);
    wb += C3.w * (ex2(AnB[15] * SB) * hB[15]);
    yacc[i] += bf2f(y1p[(size_t)(lbase + t) * D_INNER + d]) + wb;
  }
#pragma unroll
  for (int i = 0; i < 16; ++i) {
    const int l = lbase + tq * 16 + i;
    const float z = bf2f(xz_bf[((size_t)b * L_SEQ + l) * 3072 + 1536 + d]);
    yg[((size_t)b * L_SEQ + l) * D_INNER + d] = f2bf(yacc[i] * z);
  }
}

// ---------------------------------------------------------------------------
extern "C" void kernel_launch(void* const* d_in, const int* in_sizes, int n_in,
                              void* d_out, int out_size, void* d_ws,
                              size_t ws_size, hipStream_t stream) {
  const float* x          = (const float*)d_in[0];
  const float* in_proj_w  = (const float*)d_in[1];
  const float* conv_w     = (const float*)d_in[2];
  const float* conv_b     = (const float*)d_in[3];
  const float* x_proj_w   = (const float*)d_in[4];
  const float* dt_proj_w  = (const float*)d_in[5];
  const float* dt_proj_b  = (const float*)d_in[6];
  const float* A_logs     = (const float*)d_in[7];
  const float* Ds         = (const float*)d_in[8];
  const float* out_proj_w = (const float*)d_in[9];
  float* out = (float*)d_out;

  const int M = MTOT;
  const size_t NST = (size_t)2 * B_SZ * NCH * NDG;  // 6144

  float* ws    = (float*)d_ws;
  float* hfin  = ws;                          // NST*1024
  float* hin   = hfin + NST * 1024;           // NST*1024
  float* Tsum  = hin + NST * 1024;            // NST*64
  float* bcf   = Tsum + NST * 64;             // 2*M*32 f32
  ushort* x_bf     = (ushort*)(bcf + (size_t)2 * M * 32);
  ushort* w_in_bf  = x_bf + (size_t)M * 768;
  ushort* w_out_bf = w_in_bf + (size_t)3072 * 768;
  ushort* w_xp_bf  = w_out_bf + (size_t)768 * 1536;
  ushort* w_dt_bf  = w_xp_bf + (size_t)256 * 1536;
  ushort* xz_bf    = w_dt_bf + (size_t)2 * 1536 * 64;
  ushort* u_bf     = xz_bf + (size_t)M * 3072;
  ushort* delta_bf = u_bf + (size_t)M * 1536;
  ushort* dtin     = delta_bf + (size_t)2 * M * 1536;
  ushort* y_bf     = dtin + (size_t)2 * M * 64;
  ushort* yg_bf    = y_bf + (size_t)2 * M * 1536;

  dim3 blk(256);

  // 0. conversions (one kernel)
  {
    const long TOT = 3145728L + 2359296 + 1179648 + 393216 + 196608;
    cvt_all_kernel<<<dim3((TOT / 4 + 255) / 256), blk, 0, stream>>>(
        x, in_proj_w, out_proj_w, x_proj_w, dt_proj_w, x_bf, w_in_bf, w_out_bf,
        w_xp_bf, w_dt_bf);
  }

  // 1. xz = x @ in_proj_w^T  -> bf16
  gemm_k<128, 128, 0, 1, 0><<<dim3(3072 / 128, M / 128), blk, 0, stream>>>(
      x_bf, 768, w_in_bf, 768, nullptr, xz_bf, 3072, 3072, 768, nullptr,
      nullptr);

  // 2. u = silu(conv(x_conv)+bias) -> bf16
  conv_silu_kernel<<<dim3(B_SZ * (L_SEQ / 8) * (D_INNER / 8) / 256), blk, 0,
                     stream>>>(xz_bf, conv_w, conv_b, u_bf);

  // 3. dtin + bcf(f32) = u @ x_proj_w^T epilogue
  gemm_k<32, 64, 0, 0, 1><<<dim3(3, M / 32), blk, 0, stream>>>(
      u_bf, 1536, w_xp_bf, 1536, nullptr, nullptr, 1, 0, 1536, dtin, bcf);

  // 4. delta = softplus(dtin @ dtw^T + dtb) -> bf16 (both k, one dispatch)
  gemm_dt_k<<<dim3(1536 / 128, M / 64, 2), blk, 0, stream>>>(
      dtin, w_dt_bf, dt_proj_b, delta_bf);

  // 5. scan (block = 256 channels, 4 waves share one chunk)
  scan_local_kernel<<<dim3(2 * B_SZ * 6 * NCH), blk, 0, stream>>>(
      u_bf, bcf, delta_bf, A_logs, Ds, y_bf, hfin, Tsum);
  scan_stitch_kernel<<<dim3(2 * B_SZ * NDG), blk, 0, stream>>>(hfin, Tsum,
                                                               A_logs, hin);
  // 6. fused fixup(both dirs) + gate -> yg bf16
  fixup_gate_kernel<<<dim3(B_SZ * NDG * (L_SEQ / 64)), blk, 0, stream>>>(
      bcf, delta_bf, A_logs, hin, y_bf, xz_bf, yg_bf);

  // 7. out = yg @ out_proj_w^T -> fp32
  gemm_k<128, 128, 0, 0, 0><<<dim3(768 / 128, M / 128), blk, 0, stream>>>(
      yg_bf, 1536, w_out_bf, 1536, nullptr, out, 768, 768, 1536, nullptr,
      nullptr);
}

// Round 17
// 228.009 us; speedup vs baseline: 1.1205x; 1.0861x over previous
//
#include <hip/hip_runtime.h>
#include <math.h>

#define D_MODEL 768
#define D_STATE 16
#define D_INNER 1536
#define DT_RANK 48
#define B_SZ    2
#define L_SEQ   2048
#define CH      32             // scan chunk length
#define NCH     (L_SEQ / CH)   // 64 chunks
#define NDG     24             // d-groups of 64 channels (state layout)
#define MTOT    (B_SZ * L_SEQ) // 4096
#define LOG2E   1.4426950408889634f
#define LN2     0.6931471805599453f

typedef __bf16 bf16x8 __attribute__((ext_vector_type(8)));
typedef float f32x4 __attribute__((ext_vector_type(4)));
typedef ushort ushort8_t __attribute__((ext_vector_type(8)));

__device__ __forceinline__ float ex2(float x) {
  return __builtin_amdgcn_exp2f(x);  // v_exp_f32: D = 2^S0
}

__device__ __forceinline__ ushort f2bf(float f) {
  unsigned int u = __float_as_uint(f);
  unsigned int r = (u + 0x7fff + ((u >> 16) & 1)) >> 16;
  return (ushort)r;
}
__device__ __forceinline__ float bf2f(ushort u) {
  return __uint_as_float(((unsigned int)u) << 16);
}

__device__ __forceinline__ void gload_lds16(const ushort* g, ushort* l) {
  __builtin_amdgcn_global_load_lds(
      (__attribute__((address_space(1))) void*)(void*)(g),
      (__attribute__((address_space(3))) void*)(void*)(l), 16, 0, 0);
}

// fast softplus: ln(1+e^x) = ln2 * log2(1 + 2^(x*log2e)); guard large x
__device__ __forceinline__ float softplus_fast(float x) {
  return (x > 20.f) ? x : LN2 * __log2f(1.f + ex2(x * LOG2E));
}

// ---------------------------------------------------------------------------
// bf16 MFMA GEMM body, double-buffered 2-phase K-loop.
// C[M,N] = A[M,K] * B[N,K]^T (+bias, +softplus). OBF: bf16 C. DTOUT: emit
// dtin bf16 (cols 0..47 -> k0, 80..127 -> k1, pad 64) + bcbuf FP32
// ([2][M][32]: B=cols 48..63/128..143, C=cols 64..79/144..159).
// ---------------------------------------------------------------------------
template <int BM, int BN, int ACT, int OBF, int DTOUT>
__device__ __forceinline__ void gemm_body(
    const ushort* __restrict__ A, int lda, const ushort* __restrict__ B,
    int ldb, const float* __restrict__ bias, void* __restrict__ Cp, int ldc,
    int Nreal, int K, int bxi, int byi, ushort* __restrict__ dtin,
    float* __restrict__ bcp) {
  __shared__ ushort As[2][BM][32];
  __shared__ ushort Bs[2][BN][32];
  constexpr int WM = BM / 2, WN = BN / 2;
  constexpr int FM = WM / 16, FN = WN / 16;
  const int tid = threadIdx.x;
  const int lane = tid & 63;
  const int w = tid >> 6;
  const int wr = w >> 1, wc = w & 1;
  const int bm = byi * BM, bn = bxi * BN;
  const int lrow = lane >> 2;
  const int lchunk = lane & 3;
  const int fr = lane & 15;
  const int k8 = (lane >> 4) * 8;

  f32x4 acc[FM][FN] = {};

  auto stage = [&](int buf, int k0) {
    if constexpr (BM >= 64) {
#pragma unroll
      for (int g = 0; g < BM / 64; ++g) {
        const int rb = w * (BM / 4) + g * 16;
        gload_lds16(A + (size_t)(bm + rb + lrow) * lda + k0 + lchunk * 8,
                    &As[buf][rb][0]);
      }
    } else {  // BM == 32
      if (w < 2)
        gload_lds16(A + (size_t)(bm + w * 16 + lrow) * lda + k0 + lchunk * 8,
                    &As[buf][w * 16][0]);
    }
#pragma unroll
    for (int g = 0; g < BN / 64; ++g) {
      const int rb = w * (BN / 4) + g * 16;
      gload_lds16(B + (size_t)(bn + rb + lrow) * ldb + k0 + lchunk * 8,
                  &Bs[buf][rb][0]);
    }
  };

  stage(0, 0);
  __syncthreads();
  int cur = 0;
  for (int k0 = 0; k0 < K; k0 += 32) {
    if (k0 + 32 < K) stage(cur ^ 1, k0 + 32);
    bf16x8 af[FM], bfr[FN];
#pragma unroll
    for (int m = 0; m < FM; ++m)
      af[m] =
          *reinterpret_cast<const bf16x8*>(&As[cur][wr * WM + m * 16 + fr][k8]);
#pragma unroll
    for (int n = 0; n < FN; ++n)
      bfr[n] =
          *reinterpret_cast<const bf16x8*>(&Bs[cur][wc * WN + n * 16 + fr][k8]);
#pragma unroll
    for (int m = 0; m < FM; ++m)
#pragma unroll
      for (int n = 0; n < FN; ++n)
        acc[m][n] = __builtin_amdgcn_mfma_f32_16x16x32_bf16(af[m], bfr[n],
                                                            acc[m][n], 0, 0, 0);
    __syncthreads();
    cur ^= 1;
  }

  const int row4 = (lane >> 4) * 4;
#pragma unroll
  for (int m = 0; m < FM; ++m) {
#pragma unroll
    for (int n = 0; n < FN; ++n) {
      const int gn = bn + wc * WN + n * 16 + fr;
      const int gm0 = bm + wr * WM + m * 16 + row4;
#pragma unroll
      for (int j = 0; j < 4; ++j) {
        const float v = acc[m][n][j];
        const int gm = gm0 + j;
        if (DTOUT) {
          if (gn < 64)
            dtin[(size_t)gm * 64 + gn] = (gn < 48) ? f2bf(v) : (ushort)0;
          else if (gn >= 80 && gn < 144)
            dtin[(size_t)MTOT * 64 + (size_t)gm * 64 + (gn - 80)] =
                (gn < 128) ? f2bf(v) : (ushort)0;
          if (gn >= 48 && gn < 80)
            bcp[(size_t)gm * 32 + (gn - 48)] = v;
          else if (gn >= 128 && gn < 160)
            bcp[(size_t)MTOT * 32 + (size_t)gm * 32 + (gn - 128)] = v;
        }
        if (gn < Nreal) {
          float vv = v + (bias ? bias[gn] : 0.f);
          if (ACT == 1) vv = softplus_fast(vv);
          if (OBF)
            ((ushort*)Cp)[(size_t)gm * ldc + gn] = f2bf(vv);
          else
            ((float*)Cp)[(size_t)gm * ldc + gn] = vv;
        }
      }
    }
  }
}

template <int BM, int BN, int ACT, int OBF, int DTOUT>
__global__ __launch_bounds__(256) void gemm_k(
    const ushort* __restrict__ A, int lda, const ushort* __restrict__ B,
    int ldb, const float* __restrict__ bias, void* __restrict__ Cp, int ldc,
    int Nreal, int K, ushort* __restrict__ dtin, float* __restrict__ bcp) {
  gemm_body<BM, BN, ACT, OBF, DTOUT>(A, lda, B, ldb, bias, Cp, ldc, Nreal, K,
                                     blockIdx.x, blockIdx.y, dtin, bcp);
}

// dt_proj both directions in one dispatch (blockIdx.z = k); 64x128 tile
__global__ __launch_bounds__(256) void gemm_dt_k(
    const ushort* __restrict__ dtin, const ushort* __restrict__ w_dt,
    const float* __restrict__ dtb, ushort* __restrict__ delta) {
  const int k = blockIdx.z;
  gemm_body<64, 128, 1, 1, 0>(
      dtin + (size_t)k * MTOT * 64, 64, w_dt + (size_t)k * D_INNER * 64, 64,
      dtb + k * D_INNER, delta + (size_t)k * MTOT * D_INNER, D_INNER, D_INNER,
      64, blockIdx.x, blockIdx.y, nullptr, nullptr);
}

// ---------------------------------------------------------------------------
// One-shot fp32->bf16 conversion of x + all weights (with padding).
// ---------------------------------------------------------------------------
__global__ __launch_bounds__(256) void cvt_all_kernel(
    const float* __restrict__ x, const float* __restrict__ w_in,
    const float* __restrict__ w_out, const float* __restrict__ w_xp,
    const float* __restrict__ w_dt, ushort* __restrict__ x_bf,
    ushort* __restrict__ w_in_bf, ushort* __restrict__ w_out_bf,
    ushort* __restrict__ w_xp_bf, ushort* __restrict__ w_dt_bf) {
  const long N0 = 3145728, N1 = 2359296, N2 = 1179648, N3 = 393216, N4 = 196608;
  long i = ((long)blockIdx.x * 256 + threadIdx.x) * 4;
  if (i < N0) {
    const float4 v = *(const float4*)(x + i);
    ushort4 o = {f2bf(v.x), f2bf(v.y), f2bf(v.z), f2bf(v.w)};
    *(ushort4*)(x_bf + i) = o;
    return;
  }
  i -= N0;
  if (i < N1) {
    const float4 v = *(const float4*)(w_in + i);
    ushort4 o = {f2bf(v.x), f2bf(v.y), f2bf(v.z), f2bf(v.w)};
    *(ushort4*)(w_in_bf + i) = o;
    return;
  }
  i -= N1;
  if (i < N2) {
    const float4 v = *(const float4*)(w_out + i);
    ushort4 o = {f2bf(v.x), f2bf(v.y), f2bf(v.z), f2bf(v.w)};
    *(ushort4*)(w_out_bf + i) = o;
    return;
  }
  i -= N2;
  if (i < N3) {
    const long row = i / 1536;
    ushort4 o = {0, 0, 0, 0};
    if (row < 160) {
      const float4 v = *(const float4*)(w_xp + i);
      o.x = f2bf(v.x); o.y = f2bf(v.y); o.z = f2bf(v.z); o.w = f2bf(v.w);
    }
    *(ushort4*)(w_xp_bf + i) = o;
    return;
  }
  i -= N3;
  if (i < N4) {
    const int col = (int)(i & 63);
    const long row = i >> 6;
    ushort4 o = {0, 0, 0, 0};
    if (col < 48) {
      const float4 v = *(const float4*)(w_dt + row * 48 + col);
      o.x = f2bf(v.x); o.y = f2bf(v.y); o.z = f2bf(v.z); o.w = f2bf(v.w);
    }
    *(ushort4*)(w_dt_bf + i) = o;
  }
}

// ---------------------------------------------------------------------------
// Depthwise conv (k=3, pad=1) + bias + SiLU, bf16 in/out. 8ch x 8 rows.
// ---------------------------------------------------------------------------
__global__ __launch_bounds__(256) void conv_silu_kernel(
    const ushort* __restrict__ xz, const float* __restrict__ cw,
    const float* __restrict__ cb, ushort* __restrict__ u_bf) {
  const int nd8 = D_INNER / 8;  // 192
  const int idx = blockIdx.x * 256 + threadIdx.x;
  const int d8 = idx % nd8;
  const int lg = (idx / nd8) % (L_SEQ / 8);
  const int b = idx / (nd8 * (L_SEQ / 8));
  const int d = d8 * 8;
  const int l0 = lg * 8;

  float w0[8], w1[8], w2[8], bs[8];
#pragma unroll
  for (int j = 0; j < 8; ++j) {
    w0[j] = cw[(d + j) * 3 + 0];
    w1[j] = cw[(d + j) * 3 + 1];
    w2[j] = cw[(d + j) * 3 + 2];
    bs[j] = cb[d + j];
  }
  const ushort* base = xz + ((size_t)b * L_SEQ) * 3072 + d;
  const ushort8_t zv = {0, 0, 0, 0, 0, 0, 0, 0};
  ushort8_t prev = (l0 > 0) ? *(const ushort8_t*)(base + (size_t)(l0 - 1) * 3072) : zv;
  ushort8_t curv = *(const ushort8_t*)(base + (size_t)l0 * 3072);
#pragma unroll
  for (int i = 0; i < 8; ++i) {
    const int l = l0 + i;
    const ushort8_t nxt =
        (l + 1 < L_SEQ) ? *(const ushort8_t*)(base + (size_t)(l + 1) * 3072) : zv;
    ushort8_t o;
#pragma unroll
    for (int j = 0; j < 8; ++j) {
      const float a = bs[j] + bf2f(prev[j]) * w0[j] + bf2f(curv[j]) * w1[j] +
                      bf2f(nxt[j]) * w2[j];
      o[j] = f2bf(a / (1.f + __expf(-a)));
    }
    *(ushort8_t*)(u_bf + ((size_t)b * L_SEQ + l) * D_INNER + d) = o;
    prev = curv;
    curv = nxt;
  }
}

// ---------------------------------------------------------------------------
// K1: local scan. Block = 256 threads = 256 CHANNELS; all 4 waves share one
// chunk of 32 steps. LDS: delta/u raw bf16 + BC raw f32, ALL staged via
// global_load_lds (zero staging VALU). Inner loop: 2 u16 reads + 8 broadcast
// b128 reads + 16 exp2 + 32 FMA per step; no shuffles, one barrier total.
// LDS = 36 KB -> 4 blocks/CU (16 waves, 50% cap).
// ---------------------------------------------------------------------------
__global__ __launch_bounds__(256) void scan_local_kernel(
    const ushort* __restrict__ u_bf, const float* __restrict__ bcf,
    const ushort* __restrict__ delta_bf, const float* __restrict__ A_logs,
    const float* __restrict__ Ds, ushort* __restrict__ y,
    float* __restrict__ hfin, float* __restrict__ Tsum) {
  __shared__ ushort sD[CH][256];   // 16 KB, scan-order rows
  __shared__ ushort sU[CH][256];   // 16 KB
  __shared__ float sBC[CH][32];    // 4 KB: B (0..15) | C (16..31)
  const int tid = threadIdx.x;
  const int w = tid >> 6;
  const int l = tid & 63;
  const int bid = blockIdx.x;
  const int ch = bid & (NCH - 1);   // 64 chunks
  const int rest = bid >> 6;
  const int dgB6 = rest % 6;        // 256-channel group
  const int kb = rest / 6;
  const int b = kb & 1;
  const int k = kb >> 1;
  const int d0 = dgB6 * 256;
  const int d = d0 + tid;
  const int row = k * D_INNER + d;

  float An[16];
#pragma unroll
  for (int q = 0; q < 4; ++q) {
    const float4 a = *(const float4*)(A_logs + (size_t)row * D_STATE + q * 4);
    An[q * 4 + 0] = -__expf(a.x) * LOG2E;
    An[q * 4 + 1] = -__expf(a.y) * LOG2E;
    An[q * 4 + 2] = -__expf(a.z) * LOG2E;
    An[q * 4 + 3] = -__expf(a.w) * LOG2E;
  }
  const float Dk = Ds[row];

  const int t0 = ch * CH;
  const int lbase = k ? (L_SEQ - CH - t0) : t0;
  const ushort* dptr = delta_bf + (size_t)(k * B_SZ + b) * L_SEQ * D_INNER;
  const ushort* uptr = u_bf + (size_t)b * L_SEQ * D_INNER;
  const float* bck = bcf + ((size_t)k * MTOT + (size_t)b * L_SEQ) * 32;
  ushort* yptr = y + (size_t)(k * B_SZ + b) * L_SEQ * D_INNER;

  // stage delta/u: 4 sweeps; wave w writes rows i*8 + w*2 + (l>>5)
  {
    const int rr = w * 2 + (l >> 5);
    const int seg = l & 31;
#pragma unroll
    for (int i = 0; i < 4; ++i) {
      const int r2 = i * 8 + rr;
      const int gr = k ? (CH - 1 - r2) : r2;
      const size_t off = (size_t)(lbase + gr) * D_INNER + d0 + seg * 8;
      gload_lds16(dptr + off, &sD[0][0] + i * 2048 + w * 512);
      gload_lds16(uptr + off, &sU[0][0] + i * 2048 + w * 512);
    }
  }
  // stage BC (raw f32): one sweep; wave w writes rows w*8 + (l>>3)
  {
    const int r2 = w * 8 + (l >> 3);
    const int gr = k ? (CH - 1 - r2) : r2;
    gload_lds16(
        (const ushort*)(bck + (size_t)(lbase + gr) * 32 + (l & 7) * 4),
        (ushort*)(&sBC[0][0] + w * 256));
  }
  __syncthreads();

  float h[16] = {};
  float S = 0.f;

  for (int s = 0; s < CH; ++s) {
    const float dlt = bf2f(sD[s][tid]);
    const float uu = bf2f(sU[s][tid]);
    S += dlt;
    const float du = dlt * uu;
    const float4 B0 = *(const float4*)&sBC[s][0];
    const float4 B1 = *(const float4*)&sBC[s][4];
    const float4 B2 = *(const float4*)&sBC[s][8];
    const float4 B3 = *(const float4*)&sBC[s][12];
    const float4 C0 = *(const float4*)&sBC[s][16];
    const float4 C1 = *(const float4*)&sBC[s][20];
    const float4 C2 = *(const float4*)&sBC[s][24];
    const float4 C3 = *(const float4*)&sBC[s][28];
    float yt = 0.f;
    h[0] = h[0] * ex2(dlt * An[0]) + du * B0.x;   yt += h[0] * C0.x;
    h[1] = h[1] * ex2(dlt * An[1]) + du * B0.y;   yt += h[1] * C0.y;
    h[2] = h[2] * ex2(dlt * An[2]) + du * B0.z;   yt += h[2] * C0.z;
    h[3] = h[3] * ex2(dlt * An[3]) + du * B0.w;   yt += h[3] * C0.w;
    h[4] = h[4] * ex2(dlt * An[4]) + du * B1.x;   yt += h[4] * C1.x;
    h[5] = h[5] * ex2(dlt * An[5]) + du * B1.y;   yt += h[5] * C1.y;
    h[6] = h[6] * ex2(dlt * An[6]) + du * B1.z;   yt += h[6] * C1.z;
    h[7] = h[7] * ex2(dlt * An[7]) + du * B1.w;   yt += h[7] * C1.w;
    h[8] = h[8] * ex2(dlt * An[8]) + du * B2.x;   yt += h[8] * C2.x;
    h[9] = h[9] * ex2(dlt * An[9]) + du * B2.y;   yt += h[9] * C2.y;
    h[10] = h[10] * ex2(dlt * An[10]) + du * B2.z; yt += h[10] * C2.z;
    h[11] = h[11] * ex2(dlt * An[11]) + du * B2.w; yt += h[11] * C2.w;
    h[12] = h[12] * ex2(dlt * An[12]) + du * B3.x; yt += h[12] * C3.x;
    h[13] = h[13] * ex2(dlt * An[13]) + du * B3.y; yt += h[13] * C3.y;
    h[14] = h[14] * ex2(dlt * An[14]) + du * B3.z; yt += h[14] * C3.z;
    h[15] = h[15] * ex2(dlt * An[15]) + du * B3.w; yt += h[15] * C3.w;
    const int t = t0 + s;
    const int ll = k ? (L_SEQ - 1 - t) : t;
    yptr[(size_t)ll * D_INNER + d] = f2bf(yt + uu * Dk);
  }

  const int dg64 = dgB6 * 4 + w;  // 64-ch subgroup in [0,24)
  const size_t cidxB = ((size_t)(k * B_SZ + b) * NCH + ch) * NDG + dg64;
#pragma unroll
  for (int q = 0; q < 4; ++q)
    *(float4*)(hfin + cidxB * 1024 + l * 16 + q * 4) =
        make_float4(h[q * 4], h[q * 4 + 1], h[q * 4 + 2], h[q * 4 + 3]);
  Tsum[cidxB * 64 + l] = S;
}

// ---------------------------------------------------------------------------
// K2: stitch. Block = (k,b,dgB). Thread = (dl = tid>>2, nq = tid&3).
// ---------------------------------------------------------------------------
__global__ __launch_bounds__(256) void scan_stitch_kernel(
    const float* __restrict__ hfin, const float* __restrict__ Tsum,
    const float* __restrict__ A_logs, float* __restrict__ hin) {
  const int tid = threadIdx.x;
  const int dl = tid >> 2;
  const int nq = tid & 3;
  const int bid = blockIdx.x;
  const int dgB = bid % NDG;
  const int b = (bid / NDG) & 1;
  const int k = bid / (NDG * 2);
  const int row = k * D_INNER + dgB * 64 + dl;
  const float4 alv = *(const float4*)(A_logs + (size_t)row * D_STATE + nq * 4);
  const float An0 = -__expf(alv.x) * LOG2E, An1 = -__expf(alv.y) * LOG2E;
  const float An2 = -__expf(alv.z) * LOG2E, An3 = -__expf(alv.w) * LOG2E;
  float c0 = 0.f, c1 = 0.f, c2 = 0.f, c3 = 0.f;
  for (int ch = 0; ch < NCH; ++ch) {
    const size_t cidxB = ((size_t)(k * B_SZ + b) * NCH + ch) * NDG + dgB;
    const size_t off = cidxB * 1024 + dl * 16 + nq * 4;
    *(float4*)(hin + off) = make_float4(c0, c1, c2, c3);
    const float T = Tsum[cidxB * 64 + dl];
    const float4 hf = *(const float4*)(hfin + off);
    c0 = c0 * ex2(An0 * T) + hf.x;
    c1 = c1 * ex2(An1 * T) + hf.y;
    c2 = c2 * ex2(An2 * T) + hf.z;
    c3 = c3 * ex2(An3 * T) + hf.w;
  }
}

// ---------------------------------------------------------------------------
// K3: fused fixup (both directions) + gate -> yg bf16. Tile = 64 rows, but
// chunks are 32: each wave (16 rows) uses its own chunk's carry + chunk-local
// delta cumsum (quarter-parity init). delta via gload; C f32 direct copies.
// ---------------------------------------------------------------------------
__global__ __launch_bounds__(256) void fixup_gate_kernel(
    const float* __restrict__ bcf, const ushort* __restrict__ delta_bf,
    const float* __restrict__ A_logs, const float* __restrict__ hin,
    const ushort* __restrict__ y, const ushort* __restrict__ xz_bf,
    ushort* __restrict__ yg) {
  __shared__ ushort sd0[64][64], sd1[64][64];  // bf16 delta tiles
  __shared__ float sC0f[64][16], sC1f[64][16]; // f32 C tiles
  __shared__ float sQF[64][4], sQB[64][4];
  const int tid = threadIdx.x;
  const int wid = tid >> 6;
  const int lane = tid & 63;
  const int tq = wid;
  const int dl = lane;
  const int bid = blockIdx.x;
  const int chf = bid & 31;        // 64-row tile index
  const int rest = bid >> 5;
  const int dgB = rest % NDG;
  const int b = rest / NDG;
  const int d0 = dgB * 64;
  const int d = d0 + dl;
  const int lbase = chf * 64;

  float AnF[16], AnB[16], hF[16], hB[16];
#pragma unroll
  for (int q = 0; q < 4; ++q) {
    const float4 af = *(const float4*)(A_logs + (size_t)d * D_STATE + q * 4);
    AnF[q * 4 + 0] = -__expf(af.x) * LOG2E;
    AnF[q * 4 + 1] = -__expf(af.y) * LOG2E;
    AnF[q * 4 + 2] = -__expf(af.z) * LOG2E;
    AnF[q * 4 + 3] = -__expf(af.w) * LOG2E;
    const float4 ab =
        *(const float4*)(A_logs + (size_t)(D_INNER + d) * D_STATE + q * 4);
    AnB[q * 4 + 0] = -__expf(ab.x) * LOG2E;
    AnB[q * 4 + 1] = -__expf(ab.y) * LOG2E;
    AnB[q * 4 + 2] = -__expf(ab.z) * LOG2E;
    AnB[q * 4 + 3] = -__expf(ab.w) * LOG2E;
  }
  // per-wave chunk indices (chunks of 32 rows)
  const int chF = chf * 2 + (tq >> 1);
  const int chB = NCH - 1 - chf * 2 - (tq >> 1);
  const size_t cF = ((size_t)(0 * B_SZ + b) * NCH + chF) * NDG + dgB;
  const size_t cB = ((size_t)(1 * B_SZ + b) * NCH + chB) * NDG + dgB;
#pragma unroll
  for (int q = 0; q < 4; ++q) {
    const float4 hv = *(const float4*)(hin + cF * 1024 + dl * 16 + q * 4);
    hF[q * 4 + 0] = hv.x; hF[q * 4 + 1] = hv.y;
    hF[q * 4 + 2] = hv.z; hF[q * 4 + 3] = hv.w;
    const float4 hw = *(const float4*)(hin + cB * 1024 + dl * 16 + q * 4);
    hB[q * 4 + 0] = hw.x; hB[q * 4 + 1] = hw.y;
    hB[q * 4 + 2] = hw.z; hB[q * 4 + 3] = hw.w;
  }

  const ushort* d0p =
      delta_bf + ((size_t)(0 * B_SZ + b) * L_SEQ + lbase) * D_INNER + d0;
  const ushort* d1p =
      delta_bf + ((size_t)(1 * B_SZ + b) * L_SEQ + lbase) * D_INNER + d0;
  // stage delta tiles: wave-sliced gloads (slice = (i*4+wid)*1024B = 8 rows)
  {
    const int rd = lane >> 3, seg = lane & 7;
#pragma unroll
    for (int i = 0; i < 2; ++i) {
      const int sl = i * 4 + wid;
      const int r = sl * 8 + rd;
      const size_t off = (size_t)r * D_INNER + seg * 8;
      gload_lds16(d0p + off, &sd0[0][0] + sl * 512);
      gload_lds16(d1p + off, &sd1[0][0] + sl * 512);
    }
  }
  // stage C tiles (f32 direct copies)
  {
    const float* bc0 = bcf + (size_t)b * L_SEQ * 32;
    const float* bc1 = bcf + (size_t)MTOT * 32 + (size_t)b * L_SEQ * 32;
    const int r = tid >> 2;
    const int q = tid & 3;
    *(float4*)&sC0f[r][q * 4] =
        *(const float4*)(bc0 + (size_t)(lbase + r) * 32 + 16 + q * 4);
    *(float4*)&sC1f[r][q * 4] =
        *(const float4*)(bc1 + (size_t)(lbase + r) * 32 + 16 + q * 4);
  }
  __syncthreads();
  float qf = 0.f, qb = 0.f;
#pragma unroll
  for (int i = 0; i < 16; ++i) {
    qf += bf2f(sd0[tq * 16 + i][dl]);
    qb += bf2f(sd1[tq * 16 + i][dl]);
  }
  sQF[dl][tq] = qf;
  sQB[dl][tq] = qb;
  __syncthreads();
  // chunk-local prefix: chunks are quarter-pairs {0,1} and {2,3}
  float SF = (tq & 1) ? sQF[dl][tq - 1] : 0.f;
  float SB = (tq & 1) ? 0.f : sQB[dl][tq + 1];

  const ushort* y0p = y + ((size_t)(0 * B_SZ + b) * L_SEQ) * D_INNER;
  const ushort* y1p = y + ((size_t)(1 * B_SZ + b) * L_SEQ) * D_INNER;
  float yacc[16];
#pragma unroll
  for (int i = 0; i < 16; ++i) {
    const int t = tq * 16 + i;
    SF += bf2f(sd0[t][dl]);
    const float4 C0 = *(const float4*)&sC0f[t][0];
    const float4 C1 = *(const float4*)&sC0f[t][4];
    const float4 C2 = *(const float4*)&sC0f[t][8];
    const float4 C3 = *(const float4*)&sC0f[t][12];
    float wf;
    wf  = C0.x * (ex2(AnF[0] * SF) * hF[0]);
    wf += C0.y * (ex2(AnF[1] * SF) * hF[1]);
    wf += C0.z * (ex2(AnF[2] * SF) * hF[2]);
    wf += C0.w * (ex2(AnF[3] * SF) * hF[3]);
    wf += C1.x * (ex2(AnF[4] * SF) * hF[4]);
    wf += C1.y * (ex2(AnF[5] * SF) * hF[5]);
    wf += C1.z * (ex2(AnF[6] * SF) * hF[6]);
    wf += C1.w * (ex2(AnF[7] * SF) * hF[7]);
    wf += C2.x * (ex2(AnF[8] * SF) * hF[8]);
    wf += C2.y * (ex2(AnF[9] * SF) * hF[9]);
    wf += C2.z * (ex2(AnF[10] * SF) * hF[10]);
    wf += C2.w * (ex2(AnF[11] * SF) * hF[11]);
    wf += C3.x * (ex2(AnF[12] * SF) * hF[12]);
    wf += C3.y * (ex2(AnF[13] * SF) * hF[13]);
    wf += C3.z * (ex2(AnF[14] * SF) * hF[14]);
    wf += C3.w * (ex2(AnF[15] * SF) * hF[15]);
    yacc[i] = bf2f(y0p[(size_t)(lbase + t) * D_INNER + d]) + wf;
  }
#pragma unroll
  for (int i = 15; i >= 0; --i) {
    const int t = tq * 16 + i;
    SB += bf2f(sd1[t][dl]);
    const float4 C0 = *(const float4*)&sC1f[t][0];
    const float4 C1 = *(const float4*)&sC1f[t][4];
    const float4 C2 = *(const float4*)&sC1f[t][8];
    const float4 C3 = *(const float4*)&sC1f[t][12];
    float wb;
    wb  = C0.x * (ex2(AnB[0] * SB) * hB[0]);
    wb += C0.y * (ex2(AnB[1] * SB) * hB[1]);
    wb += C0.z * (ex2(AnB[2] * SB) * hB[2]);
    wb += C0.w * (ex2(AnB[3] * SB) * hB[3]);
    wb += C1.x * (ex2(AnB[4] * SB) * hB[4]);
    wb += C1.y * (ex2(AnB[5] * SB) * hB[5]);
    wb += C1.z * (ex2(AnB[6] * SB) * hB[6]);
    wb += C1.w * (ex2(AnB[7] * SB) * hB[7]);
    wb += C2.x * (ex2(AnB[8] * SB) * hB[8]);
    wb += C2.y * (ex2(AnB[9] * SB) * hB[9]);
    wb += C2.z * (ex2(AnB[10] * SB) * hB[10]);
    wb += C2.w * (ex2(AnB[11] * SB) * hB[11]);
    wb += C3.x * (ex2(AnB[12] * SB) * hB[12]);
    wb += C3.y * (ex2(AnB[13] * SB) * hB[13]);
    wb += C3.z * (ex2(AnB[14] * SB) * hB[14]);
    wb += C3.w * (ex2(AnB[15] * SB) * hB[15]);
    yacc[i] += bf2f(y1p[(size_t)(lbase + t) * D_INNER + d]) + wb;
  }
#pragma unroll
  for (int i = 0; i < 16; ++i) {
    const int l = lbase + tq * 16 + i;
    const float z = bf2f(xz_bf[((size_t)b * L_SEQ + l) * 3072 + 1536 + d]);
    yg[((size_t)b * L_SEQ + l) * D_INNER + d] = f2bf(yacc[i] * z);
  }
}

// ---------------------------------------------------------------------------
extern "C" void kernel_launch(void* const* d_in, const int* in_sizes, int n_in,
                              void* d_out, int out_size, void* d_ws,
                              size_t ws_size, hipStream_t stream) {
  const float* x          = (const float*)d_in[0];
  const float* in_proj_w  = (const float*)d_in[1];
  const float* conv_w     = (const float*)d_in[2];
  const float* conv_b     = (const float*)d_in[3];
  const float* x_proj_w   = (const float*)d_in[4];
  const float* dt_proj_w  = (const float*)d_in[5];
  const float* dt_proj_b  = (const float*)d_in[6];
  const float* A_logs     = (const float*)d_in[7];
  const float* Ds         = (const float*)d_in[8];
  const float* out_proj_w = (const float*)d_in[9];
  float* out = (float*)d_out;

  const int M = MTOT;
  const size_t NST = (size_t)2 * B_SZ * NCH * NDG;  // 6144

  float* ws    = (float*)d_ws;
  float* hfin  = ws;                          // NST*1024
  float* hin   = hfin + NST * 1024;           // NST*1024
  float* Tsum  = hin + NST * 1024;            // NST*64
  float* bcf   = Tsum + NST * 64;             // 2*M*32 f32
  ushort* x_bf     = (ushort*)(bcf + (size_t)2 * M * 32);
  ushort* w_in_bf  = x_bf + (size_t)M * 768;
  ushort* w_out_bf = w_in_bf + (size_t)3072 * 768;
  ushort* w_xp_bf  = w_out_bf + (size_t)768 * 1536;
  ushort* w_dt_bf  = w_xp_bf + (size_t)256 * 1536;
  ushort* xz_bf    = w_dt_bf + (size_t)2 * 1536 * 64;
  ushort* u_bf     = xz_bf + (size_t)M * 3072;
  ushort* delta_bf = u_bf + (size_t)M * 1536;
  ushort* dtin     = delta_bf + (size_t)2 * M * 1536;
  ushort* y_bf     = dtin + (size_t)2 * M * 64;
  ushort* yg_bf    = y_bf + (size_t)2 * M * 1536;

  dim3 blk(256);

  // 0. conversions (one kernel)
  {
    const long TOT = 3145728L + 2359296 + 1179648 + 393216 + 196608;
    cvt_all_kernel<<<dim3((TOT / 4 + 255) / 256), blk, 0, stream>>>(
        x, in_proj_w, out_proj_w, x_proj_w, dt_proj_w, x_bf, w_in_bf, w_out_bf,
        w_xp_bf, w_dt_bf);
  }

  // 1. xz = x @ in_proj_w^T  -> bf16
  gemm_k<128, 128, 0, 1, 0><<<dim3(3072 / 128, M / 128), blk, 0, stream>>>(
      x_bf, 768, w_in_bf, 768, nullptr, xz_bf, 3072, 3072, 768, nullptr,
      nullptr);

  // 2. u = silu(conv(x_conv)+bias) -> bf16
  conv_silu_kernel<<<dim3(B_SZ * (L_SEQ / 8) * (D_INNER / 8) / 256), blk, 0,
                     stream>>>(xz_bf, conv_w, conv_b, u_bf);

  // 3. dtin + bcf(f32) = u @ x_proj_w^T epilogue
  gemm_k<32, 64, 0, 0, 1><<<dim3(3, M / 32), blk, 0, stream>>>(
      u_bf, 1536, w_xp_bf, 1536, nullptr, nullptr, 1, 0, 1536, dtin, bcf);

  // 4. delta = softplus(dtin @ dtw^T + dtb) -> bf16 (both k, one dispatch)
  gemm_dt_k<<<dim3(1536 / 128, M / 64, 2), blk, 0, stream>>>(
      dtin, w_dt_bf, dt_proj_b, delta_bf);

  // 5. scan (block = 256 channels sharing one 32-step chunk)
  scan_local_kernel<<<dim3(2 * B_SZ * 6 * NCH), blk, 0, stream>>>(
      u_bf, bcf, delta_bf, A_logs, Ds, y_bf, hfin, Tsum);
  scan_stitch_kernel<<<dim3(2 * B_SZ * NDG), blk, 0, stream>>>(hfin, Tsum,
                                                               A_logs, hin);
  // 6. fused fixup(both dirs) + gate -> yg bf16
  fixup_gate_kernel<<<dim3(B_SZ * NDG * (L_SEQ / 64)), blk, 0, stream>>>(
      bcf, delta_bf, A_logs, hin, y_bf, xz_bf, yg_bf);

  // 7. out = yg @ out_proj_w^T -> fp32
  gemm_k<128, 128, 0, 0, 0><<<dim3(768 / 128, M / 128), blk, 0, stream>>>(
      yg_bf, 1536, w_out_bf, 1536, nullptr, out, 768, 768, 1536, nullptr,
      nullptr);
}

// Round 18
// 224.602 us; speedup vs baseline: 1.1375x; 1.0152x over previous
//
#include <hip/hip_runtime.h>
#include <math.h>

#define D_MODEL 768
#define D_STATE 16
#define D_INNER 1536
#define DT_RANK 48
#define B_SZ    2
#define L_SEQ   2048
#define CH      64             // scan chunk length
#define NCH     (L_SEQ / CH)   // 32 chunks
#define NDG     24             // d-groups of 64 channels (state layout)
#define MTOT    (B_SZ * L_SEQ) // 4096
#define LOG2E   1.4426950408889634f
#define LN2     0.6931471805599453f

typedef __bf16 bf16x8 __attribute__((ext_vector_type(8)));
typedef float f32x4 __attribute__((ext_vector_type(4)));
typedef ushort ushort8_t __attribute__((ext_vector_type(8)));

__device__ __forceinline__ float ex2(float x) {
  return __builtin_amdgcn_exp2f(x);  // v_exp_f32: D = 2^S0
}

__device__ __forceinline__ ushort f2bf(float f) {
  unsigned int u = __float_as_uint(f);
  unsigned int r = (u + 0x7fff + ((u >> 16) & 1)) >> 16;
  return (ushort)r;
}
__device__ __forceinline__ float bf2f(ushort u) {
  return __uint_as_float(((unsigned int)u) << 16);
}

__device__ __forceinline__ void gload_lds16(const ushort* g, ushort* l) {
  __builtin_amdgcn_global_load_lds(
      (__attribute__((address_space(1))) void*)(void*)(g),
      (__attribute__((address_space(3))) void*)(void*)(l), 16, 0, 0);
}

// fast softplus: ln(1+e^x) = ln2 * log2(1 + 2^(x*log2e)); guard large x
__device__ __forceinline__ float softplus_fast(float x) {
  return (x > 20.f) ? x : LN2 * __log2f(1.f + ex2(x * LOG2E));
}

// ---------------------------------------------------------------------------
// bf16 MFMA GEMM body, double-buffered 2-phase K-loop.
// C[M,N] = A[M,K] * B[N,K]^T (+bias, +softplus). OBF: bf16 C. DTOUT: emit
// dtin bf16 (cols 0..47 -> k0, 80..127 -> k1, pad 64) + bcbuf FP32
// ([2][M][32]: B=cols 48..63/128..143, C=cols 64..79/144..159).
// ---------------------------------------------------------------------------
template <int BM, int BN, int ACT, int OBF, int DTOUT>
__device__ __forceinline__ void gemm_body(
    const ushort* __restrict__ A, int lda, const ushort* __restrict__ B,
    int ldb, const float* __restrict__ bias, void* __restrict__ Cp, int ldc,
    int Nreal, int K, int bxi, int byi, ushort* __restrict__ dtin,
    float* __restrict__ bcp) {
  __shared__ ushort As[2][BM][32];
  __shared__ ushort Bs[2][BN][32];
  constexpr int WM = BM / 2, WN = BN / 2;
  constexpr int FM = WM / 16, FN = WN / 16;
  const int tid = threadIdx.x;
  const int lane = tid & 63;
  const int w = tid >> 6;
  const int wr = w >> 1, wc = w & 1;
  const int bm = byi * BM, bn = bxi * BN;
  const int lrow = lane >> 2;
  const int lchunk = lane & 3;
  const int fr = lane & 15;
  const int k8 = (lane >> 4) * 8;

  f32x4 acc[FM][FN] = {};

  auto stage = [&](int buf, int k0) {
    if constexpr (BM >= 64) {
#pragma unroll
      for (int g = 0; g < BM / 64; ++g) {
        const int rb = w * (BM / 4) + g * 16;
        gload_lds16(A + (size_t)(bm + rb + lrow) * lda + k0 + lchunk * 8,
                    &As[buf][rb][0]);
      }
    } else {  // BM == 32
      if (w < 2)
        gload_lds16(A + (size_t)(bm + w * 16 + lrow) * lda + k0 + lchunk * 8,
                    &As[buf][w * 16][0]);
    }
#pragma unroll
    for (int g = 0; g < BN / 64; ++g) {
      const int rb = w * (BN / 4) + g * 16;
      gload_lds16(B + (size_t)(bn + rb + lrow) * ldb + k0 + lchunk * 8,
                  &Bs[buf][rb][0]);
    }
  };

  stage(0, 0);
  __syncthreads();
  int cur = 0;
  for (int k0 = 0; k0 < K; k0 += 32) {
    if (k0 + 32 < K) stage(cur ^ 1, k0 + 32);
    bf16x8 af[FM], bfr[FN];
#pragma unroll
    for (int m = 0; m < FM; ++m)
      af[m] =
          *reinterpret_cast<const bf16x8*>(&As[cur][wr * WM + m * 16 + fr][k8]);
#pragma unroll
    for (int n = 0; n < FN; ++n)
      bfr[n] =
          *reinterpret_cast<const bf16x8*>(&Bs[cur][wc * WN + n * 16 + fr][k8]);
#pragma unroll
    for (int m = 0; m < FM; ++m)
#pragma unroll
      for (int n = 0; n < FN; ++n)
        acc[m][n] = __builtin_amdgcn_mfma_f32_16x16x32_bf16(af[m], bfr[n],
                                                            acc[m][n], 0, 0, 0);
    __syncthreads();
    cur ^= 1;
  }

  const int row4 = (lane >> 4) * 4;
#pragma unroll
  for (int m = 0; m < FM; ++m) {
#pragma unroll
    for (int n = 0; n < FN; ++n) {
      const int gn = bn + wc * WN + n * 16 + fr;
      const int gm0 = bm + wr * WM + m * 16 + row4;
#pragma unroll
      for (int j = 0; j < 4; ++j) {
        const float v = acc[m][n][j];
        const int gm = gm0 + j;
        if (DTOUT) {
          if (gn < 64)
            dtin[(size_t)gm * 64 + gn] = (gn < 48) ? f2bf(v) : (ushort)0;
          else if (gn >= 80 && gn < 144)
            dtin[(size_t)MTOT * 64 + (size_t)gm * 64 + (gn - 80)] =
                (gn < 128) ? f2bf(v) : (ushort)0;
          if (gn >= 48 && gn < 80)
            bcp[(size_t)gm * 32 + (gn - 48)] = v;
          else if (gn >= 128 && gn < 160)
            bcp[(size_t)MTOT * 32 + (size_t)gm * 32 + (gn - 128)] = v;
        }
        if (gn < Nreal) {
          float vv = v + (bias ? bias[gn] : 0.f);
          if (ACT == 1) vv = softplus_fast(vv);
          if (OBF)
            ((ushort*)Cp)[(size_t)gm * ldc + gn] = f2bf(vv);
          else
            ((float*)Cp)[(size_t)gm * ldc + gn] = vv;
        }
      }
    }
  }
}

template <int BM, int BN, int ACT, int OBF, int DTOUT>
__global__ __launch_bounds__(256) void gemm_k(
    const ushort* __restrict__ A, int lda, const ushort* __restrict__ B,
    int ldb, const float* __restrict__ bias, void* __restrict__ Cp, int ldc,
    int Nreal, int K, ushort* __restrict__ dtin, float* __restrict__ bcp) {
  gemm_body<BM, BN, ACT, OBF, DTOUT>(A, lda, B, ldb, bias, Cp, ldc, Nreal, K,
                                     blockIdx.x, blockIdx.y, dtin, bcp);
}

// dt_proj both directions in one dispatch (blockIdx.z = k); 64x128 tile
__global__ __launch_bounds__(256) void gemm_dt_k(
    const ushort* __restrict__ dtin, const ushort* __restrict__ w_dt,
    const float* __restrict__ dtb, ushort* __restrict__ delta) {
  const int k = blockIdx.z;
  gemm_body<64, 128, 1, 1, 0>(
      dtin + (size_t)k * MTOT * 64, 64, w_dt + (size_t)k * D_INNER * 64, 64,
      dtb + k * D_INNER, delta + (size_t)k * MTOT * D_INNER, D_INNER, D_INNER,
      64, blockIdx.x, blockIdx.y, nullptr, nullptr);
}

// ---------------------------------------------------------------------------
// One-shot fp32->bf16 conversion of x + all weights (with padding).
// ---------------------------------------------------------------------------
__global__ __launch_bounds__(256) void cvt_all_kernel(
    const float* __restrict__ x, const float* __restrict__ w_in,
    const float* __restrict__ w_out, const float* __restrict__ w_xp,
    const float* __restrict__ w_dt, ushort* __restrict__ x_bf,
    ushort* __restrict__ w_in_bf, ushort* __restrict__ w_out_bf,
    ushort* __restrict__ w_xp_bf, ushort* __restrict__ w_dt_bf) {
  const long N0 = 3145728, N1 = 2359296, N2 = 1179648, N3 = 393216, N4 = 196608;
  long i = ((long)blockIdx.x * 256 + threadIdx.x) * 4;
  if (i < N0) {
    const float4 v = *(const float4*)(x + i);
    ushort4 o = {f2bf(v.x), f2bf(v.y), f2bf(v.z), f2bf(v.w)};
    *(ushort4*)(x_bf + i) = o;
    return;
  }
  i -= N0;
  if (i < N1) {
    const float4 v = *(const float4*)(w_in + i);
    ushort4 o = {f2bf(v.x), f2bf(v.y), f2bf(v.z), f2bf(v.w)};
    *(ushort4*)(w_in_bf + i) = o;
    return;
  }
  i -= N1;
  if (i < N2) {
    const float4 v = *(const float4*)(w_out + i);
    ushort4 o = {f2bf(v.x), f2bf(v.y), f2bf(v.z), f2bf(v.w)};
    *(ushort4*)(w_out_bf + i) = o;
    return;
  }
  i -= N2;
  if (i < N3) {
    const long row = i / 1536;
    ushort4 o = {0, 0, 0, 0};
    if (row < 160) {
      const float4 v = *(const float4*)(w_xp + i);
      o.x = f2bf(v.x); o.y = f2bf(v.y); o.z = f2bf(v.z); o.w = f2bf(v.w);
    }
    *(ushort4*)(w_xp_bf + i) = o;
    return;
  }
  i -= N3;
  if (i < N4) {
    const int col = (int)(i & 63);
    const long row = i >> 6;
    ushort4 o = {0, 0, 0, 0};
    if (col < 48) {
      const float4 v = *(const float4*)(w_dt + row * 48 + col);
      o.x = f2bf(v.x); o.y = f2bf(v.y); o.z = f2bf(v.z); o.w = f2bf(v.w);
    }
    *(ushort4*)(w_dt_bf + i) = o;
  }
}

// ---------------------------------------------------------------------------
// Depthwise conv (k=3, pad=1) + bias + SiLU, bf16 in/out. 8ch x 8 rows.
// ---------------------------------------------------------------------------
__global__ __launch_bounds__(256) void conv_silu_kernel(
    const ushort* __restrict__ xz, const float* __restrict__ cw,
    const float* __restrict__ cb, ushort* __restrict__ u_bf) {
  const int nd8 = D_INNER / 8;  // 192
  const int idx = blockIdx.x * 256 + threadIdx.x;
  const int d8 = idx % nd8;
  const int lg = (idx / nd8) % (L_SEQ / 8);
  const int b = idx / (nd8 * (L_SEQ / 8));
  const int d = d8 * 8;
  const int l0 = lg * 8;

  float w0[8], w1[8], w2[8], bs[8];
#pragma unroll
  for (int j = 0; j < 8; ++j) {
    w0[j] = cw[(d + j) * 3 + 0];
    w1[j] = cw[(d + j) * 3 + 1];
    w2[j] = cw[(d + j) * 3 + 2];
    bs[j] = cb[d + j];
  }
  const ushort* base = xz + ((size_t)b * L_SEQ) * 3072 + d;
  const ushort8_t zv = {0, 0, 0, 0, 0, 0, 0, 0};
  ushort8_t prev = (l0 > 0) ? *(const ushort8_t*)(base + (size_t)(l0 - 1) * 3072) : zv;
  ushort8_t curv = *(const ushort8_t*)(base + (size_t)l0 * 3072);
#pragma unroll
  for (int i = 0; i < 8; ++i) {
    const int l = l0 + i;
    const ushort8_t nxt =
        (l + 1 < L_SEQ) ? *(const ushort8_t*)(base + (size_t)(l + 1) * 3072) : zv;
    ushort8_t o;
#pragma unroll
    for (int j = 0; j < 8; ++j) {
      const float a = bs[j] + bf2f(prev[j]) * w0[j] + bf2f(curv[j]) * w1[j] +
                      bf2f(nxt[j]) * w2[j];
      o[j] = f2bf(a / (1.f + __expf(-a)));
    }
    *(ushort8_t*)(u_bf + ((size_t)b * L_SEQ + l) * D_INNER + d) = o;
    prev = curv;
    curv = nxt;
  }
}

// ---------------------------------------------------------------------------
// K1: local scan. Block = 256 threads = 256 CHANNELS; all 4 waves share one
// chunk of 64 steps, processed in two 32-step halves (LDS reuse). All inputs
// staged via global_load_lds (zero staging VALU): delta/u raw bf16 per half,
// BC raw f32 once. LDS = 40 KB -> 4 blocks/CU; grid 768 = fully resident.
// ---------------------------------------------------------------------------
__global__ __launch_bounds__(256) void scan_local_kernel(
    const ushort* __restrict__ u_bf, const float* __restrict__ bcf,
    const ushort* __restrict__ delta_bf, const float* __restrict__ A_logs,
    const float* __restrict__ Ds, ushort* __restrict__ y,
    float* __restrict__ hfin, float* __restrict__ Tsum) {
  __shared__ ushort sD[32][256];   // 16 KB, scan-order rows (current half)
  __shared__ ushort sU[32][256];   // 16 KB
  __shared__ float sBC[CH][32];    // 8 KB: B (0..15) | C (16..31)
  const int tid = threadIdx.x;
  const int w = tid >> 6;
  const int l = tid & 63;
  const int bid = blockIdx.x;
  const int ch = bid & (NCH - 1);   // 32 chunks
  const int rest = bid >> 5;
  const int dgB6 = rest % 6;        // 256-channel group
  const int kb = rest / 6;
  const int b = kb & 1;
  const int k = kb >> 1;
  const int d0 = dgB6 * 256;
  const int d = d0 + tid;
  const int row = k * D_INNER + d;

  float An[16];
#pragma unroll
  for (int q = 0; q < 4; ++q) {
    const float4 a = *(const float4*)(A_logs + (size_t)row * D_STATE + q * 4);
    An[q * 4 + 0] = -__expf(a.x) * LOG2E;
    An[q * 4 + 1] = -__expf(a.y) * LOG2E;
    An[q * 4 + 2] = -__expf(a.z) * LOG2E;
    An[q * 4 + 3] = -__expf(a.w) * LOG2E;
  }
  const float Dk = Ds[row];

  const int t0 = ch * CH;
  const int lbase = k ? (L_SEQ - CH - t0) : t0;
  const ushort* dptr = delta_bf + (size_t)(k * B_SZ + b) * L_SEQ * D_INNER;
  const ushort* uptr = u_bf + (size_t)b * L_SEQ * D_INNER;
  const float* bck = bcf + ((size_t)k * MTOT + (size_t)b * L_SEQ) * 32;
  ushort* yptr = y + (size_t)(k * B_SZ + b) * L_SEQ * D_INNER;

  // stage BC (raw f32) once: 2 sweeps of 32 rows
  {
#pragma unroll
    for (int i = 0; i < 2; ++i) {
      const int r2 = i * 32 + w * 8 + (l >> 3);
      const int gr = k ? (CH - 1 - r2) : r2;
      gload_lds16(
          (const ushort*)(bck + (size_t)(lbase + gr) * 32 + (l & 7) * 4),
          (ushort*)(&sBC[0][0] + i * 1024 + w * 256));
    }
  }

  float h[16] = {};
  float S = 0.f;

  for (int half = 0; half < 2; ++half) {
    // stage delta/u for this half: 4 sweeps of 8 rows each
    {
      const int rr = w * 2 + (l >> 5);
      const int seg = l & 31;
#pragma unroll
      for (int i = 0; i < 4; ++i) {
        const int r2 = i * 8 + rr;  // row within half
        const int gr = k ? (CH - 1 - (half * 32 + r2)) : (half * 32 + r2);
        const size_t off = (size_t)(lbase + gr) * D_INNER + d0 + seg * 8;
        gload_lds16(dptr + off, &sD[0][0] + i * 2048 + w * 512);
        gload_lds16(uptr + off, &sU[0][0] + i * 2048 + w * 512);
      }
    }
    __syncthreads();
    for (int s = 0; s < 32; ++s) {
      const float dlt = bf2f(sD[s][tid]);
      const float uu = bf2f(sU[s][tid]);
      S += dlt;
      const float du = dlt * uu;
      const int sb = half * 32 + s;
      const float4 B0 = *(const float4*)&sBC[sb][0];
      const float4 B1 = *(const float4*)&sBC[sb][4];
      const float4 B2 = *(const float4*)&sBC[sb][8];
      const float4 B3 = *(const float4*)&sBC[sb][12];
      const float4 C0 = *(const float4*)&sBC[sb][16];
      const float4 C1 = *(const float4*)&sBC[sb][20];
      const float4 C2 = *(const float4*)&sBC[sb][24];
      const float4 C3 = *(const float4*)&sBC[sb][28];
      float yt = 0.f;
      h[0] = h[0] * ex2(dlt * An[0]) + du * B0.x;   yt += h[0] * C0.x;
      h[1] = h[1] * ex2(dlt * An[1]) + du * B0.y;   yt += h[1] * C0.y;
      h[2] = h[2] * ex2(dlt * An[2]) + du * B0.z;   yt += h[2] * C0.z;
      h[3] = h[3] * ex2(dlt * An[3]) + du * B0.w;   yt += h[3] * C0.w;
      h[4] = h[4] * ex2(dlt * An[4]) + du * B1.x;   yt += h[4] * C1.x;
      h[5] = h[5] * ex2(dlt * An[5]) + du * B1.y;   yt += h[5] * C1.y;
      h[6] = h[6] * ex2(dlt * An[6]) + du * B1.z;   yt += h[6] * C1.z;
      h[7] = h[7] * ex2(dlt * An[7]) + du * B1.w;   yt += h[7] * C1.w;
      h[8] = h[8] * ex2(dlt * An[8]) + du * B2.x;   yt += h[8] * C2.x;
      h[9] = h[9] * ex2(dlt * An[9]) + du * B2.y;   yt += h[9] * C2.y;
      h[10] = h[10] * ex2(dlt * An[10]) + du * B2.z; yt += h[10] * C2.z;
      h[11] = h[11] * ex2(dlt * An[11]) + du * B2.w; yt += h[11] * C2.w;
      h[12] = h[12] * ex2(dlt * An[12]) + du * B3.x; yt += h[12] * C3.x;
      h[13] = h[13] * ex2(dlt * An[13]) + du * B3.y; yt += h[13] * C3.y;
      h[14] = h[14] * ex2(dlt * An[14]) + du * B3.z; yt += h[14] * C3.z;
      h[15] = h[15] * ex2(dlt * An[15]) + du * B3.w; yt += h[15] * C3.w;
      const int t = t0 + half * 32 + s;
      const int ll = k ? (L_SEQ - 1 - t) : t;
      yptr[(size_t)ll * D_INNER + d] = f2bf(yt + uu * Dk);
    }
    __syncthreads();
  }

  const int dg64 = dgB6 * 4 + w;  // 64-ch subgroup in [0,24)
  const size_t cidxB = ((size_t)(k * B_SZ + b) * NCH + ch) * NDG + dg64;
#pragma unroll
  for (int q = 0; q < 4; ++q)
    *(float4*)(hfin + cidxB * 1024 + l * 16 + q * 4) =
        make_float4(h[q * 4], h[q * 4 + 1], h[q * 4 + 2], h[q * 4 + 3]);
  Tsum[cidxB * 64 + l] = S;
}

// ---------------------------------------------------------------------------
// K2: stitch. Block = (k,b,dgB). Thread = (dl = tid>>2, nq = tid&3).
// ---------------------------------------------------------------------------
__global__ __launch_bounds__(256) void scan_stitch_kernel(
    const float* __restrict__ hfin, const float* __restrict__ Tsum,
    const float* __restrict__ A_logs, float* __restrict__ hin) {
  const int tid = threadIdx.x;
  const int dl = tid >> 2;
  const int nq = tid & 3;
  const int bid = blockIdx.x;
  const int dgB = bid % NDG;
  const int b = (bid / NDG) & 1;
  const int k = bid / (NDG * 2);
  const int row = k * D_INNER + dgB * 64 + dl;
  const float4 alv = *(const float4*)(A_logs + (size_t)row * D_STATE + nq * 4);
  const float An0 = -__expf(alv.x) * LOG2E, An1 = -__expf(alv.y) * LOG2E;
  const float An2 = -__expf(alv.z) * LOG2E, An3 = -__expf(alv.w) * LOG2E;
  float c0 = 0.f, c1 = 0.f, c2 = 0.f, c3 = 0.f;
  for (int ch = 0; ch < NCH; ++ch) {
    const size_t cidxB = ((size_t)(k * B_SZ + b) * NCH + ch) * NDG + dgB;
    const size_t off = cidxB * 1024 + dl * 16 + nq * 4;
    *(float4*)(hin + off) = make_float4(c0, c1, c2, c3);
    const float T = Tsum[cidxB * 64 + dl];
    const float4 hf = *(const float4*)(hfin + off);
    c0 = c0 * ex2(An0 * T) + hf.x;
    c1 = c1 * ex2(An1 * T) + hf.y;
    c2 = c2 * ex2(An2 * T) + hf.z;
    c3 = c3 * ex2(An3 * T) + hf.w;
  }
}

// ---------------------------------------------------------------------------
// K3: fused fixup (both directions) + gate -> yg bf16. Tile = chunk = 64 rows.
// delta via gload; C f32 direct copies; quarter-prefix cumsum.
// ---------------------------------------------------------------------------
__global__ __launch_bounds__(256) void fixup_gate_kernel(
    const float* __restrict__ bcf, const ushort* __restrict__ delta_bf,
    const float* __restrict__ A_logs, const float* __restrict__ hin,
    const ushort* __restrict__ y, const ushort* __restrict__ xz_bf,
    ushort* __restrict__ yg) {
  __shared__ ushort sd0[64][64], sd1[64][64];  // bf16 delta tiles
  __shared__ float sC0f[64][16], sC1f[64][16]; // f32 C tiles
  __shared__ float sQF[64][4], sQB[64][4];
  const int tid = threadIdx.x;
  const int wid = tid >> 6;
  const int lane = tid & 63;
  const int tq = wid;
  const int dl = lane;
  const int bid = blockIdx.x;
  const int ch = bid & (NCH - 1);  // tile == chunk
  const int rest = bid >> 5;
  const int dgB = rest % NDG;
  const int b = rest / NDG;
  const int d0 = dgB * 64;
  const int d = d0 + dl;
  const int lbase = ch * CH;
  const int chb = NCH - 1 - ch;

  float AnF[16], AnB[16], hF[16], hB[16];
#pragma unroll
  for (int q = 0; q < 4; ++q) {
    const float4 af = *(const float4*)(A_logs + (size_t)d * D_STATE + q * 4);
    AnF[q * 4 + 0] = -__expf(af.x) * LOG2E;
    AnF[q * 4 + 1] = -__expf(af.y) * LOG2E;
    AnF[q * 4 + 2] = -__expf(af.z) * LOG2E;
    AnF[q * 4 + 3] = -__expf(af.w) * LOG2E;
    const float4 ab =
        *(const float4*)(A_logs + (size_t)(D_INNER + d) * D_STATE + q * 4);
    AnB[q * 4 + 0] = -__expf(ab.x) * LOG2E;
    AnB[q * 4 + 1] = -__expf(ab.y) * LOG2E;
    AnB[q * 4 + 2] = -__expf(ab.z) * LOG2E;
    AnB[q * 4 + 3] = -__expf(ab.w) * LOG2E;
  }
  const size_t cF = ((size_t)(0 * B_SZ + b) * NCH + ch) * NDG + dgB;
  const size_t cB = ((size_t)(1 * B_SZ + b) * NCH + chb) * NDG + dgB;
#pragma unroll
  for (int q = 0; q < 4; ++q) {
    const float4 hv = *(const float4*)(hin + cF * 1024 + dl * 16 + q * 4);
    hF[q * 4 + 0] = hv.x; hF[q * 4 + 1] = hv.y;
    hF[q * 4 + 2] = hv.z; hF[q * 4 + 3] = hv.w;
    const float4 hw = *(const float4*)(hin + cB * 1024 + dl * 16 + q * 4);
    hB[q * 4 + 0] = hw.x; hB[q * 4 + 1] = hw.y;
    hB[q * 4 + 2] = hw.z; hB[q * 4 + 3] = hw.w;
  }

  const ushort* d0p =
      delta_bf + ((size_t)(0 * B_SZ + b) * L_SEQ + lbase) * D_INNER + d0;
  const ushort* d1p =
      delta_bf + ((size_t)(1 * B_SZ + b) * L_SEQ + lbase) * D_INNER + d0;
  // stage delta tiles: wave-sliced gloads (slice = (i*4+wid)*1024B = 8 rows)
  {
    const int rd = lane >> 3, seg = lane & 7;
#pragma unroll
    for (int i = 0; i < 2; ++i) {
      const int sl = i * 4 + wid;
      const int r = sl * 8 + rd;
      const size_t off = (size_t)r * D_INNER + seg * 8;
      gload_lds16(d0p + off, &sd0[0][0] + sl * 512);
      gload_lds16(d1p + off, &sd1[0][0] + sl * 512);
    }
  }
  // stage C tiles (f32 direct copies)
  {
    const float* bc0 = bcf + (size_t)b * L_SEQ * 32;
    const float* bc1 = bcf + (size_t)MTOT * 32 + (size_t)b * L_SEQ * 32;
    const int r = tid >> 2;
    const int q = tid & 3;
    *(float4*)&sC0f[r][q * 4] =
        *(const float4*)(bc0 + (size_t)(lbase + r) * 32 + 16 + q * 4);
    *(float4*)&sC1f[r][q * 4] =
        *(const float4*)(bc1 + (size_t)(lbase + r) * 32 + 16 + q * 4);
  }
  __syncthreads();
  float qf = 0.f, qb = 0.f;
#pragma unroll
  for (int i = 0; i < 16; ++i) {
    qf += bf2f(sd0[tq * 16 + i][dl]);
    qb += bf2f(sd1[tq * 16 + i][dl]);
  }
  sQF[dl][tq] = qf;
  sQB[dl][tq] = qb;
  __syncthreads();
  float SF = 0.f, SB = 0.f;
#pragma unroll
  for (int j = 0; j < 4; ++j) {
    if (j < tq) SF += sQF[dl][j];
    if (j > tq) SB += sQB[dl][j];
  }

  const ushort* y0p = y + ((size_t)(0 * B_SZ + b) * L_SEQ) * D_INNER;
  const ushort* y1p = y + ((size_t)(1 * B_SZ + b) * L_SEQ) * D_INNER;
  float yacc[16];
#pragma unroll
  for (int i = 0; i < 16; ++i) {
    const int t = tq * 16 + i;
    SF += bf2f(sd0[t][dl]);
    const float4 C0 = *(const float4*)&sC0f[t][0];
    const float4 C1 = *(const float4*)&sC0f[t][4];
    const float4 C2 = *(const float4*)&sC0f[t][8];
    const float4 C3 = *(const float4*)&sC0f[t][12];
    float wf;
    wf  = C0.x * (ex2(AnF[0] * SF) * hF[0]);
    wf += C0.y * (ex2(AnF[1] * SF) * hF[1]);
    wf += C0.z * (ex2(AnF[2] * SF) * hF[2]);
    wf += C0.w * (ex2(AnF[3] * SF) * hF[3]);
    wf += C1.x * (ex2(AnF[4] * SF) * hF[4]);
    wf += C1.y * (ex2(AnF[5] * SF) * hF[5]);
    wf += C1.z * (ex2(AnF[6] * SF) * hF[6]);
    wf += C1.w * (ex2(AnF[7] * SF) * hF[7]);
    wf += C2.x * (ex2(AnF[8] * SF) * hF[8]);
    wf += C2.y * (ex2(AnF[9] * SF) * hF[9]);
    wf += C2.z * (ex2(AnF[10] * SF) * hF[10]);
    wf += C2.w * (ex2(AnF[11] * SF) * hF[11]);
    wf += C3.x * (ex2(AnF[12] * SF) * hF[12]);
    wf += C3.y * (ex2(AnF[13] * SF) * hF[13]);
    wf += C3.z * (ex2(AnF[14] * SF) * hF[14]);
    wf += C3.w * (ex2(AnF[15] * SF) * hF[15]);
    yacc[i] = bf2f(y0p[(size_t)(lbase + t) * D_INNER + d]) + wf;
  }
#pragma unroll
  for (int i = 15; i >= 0; --i) {
    const int t = tq * 16 + i;
    SB += bf2f(sd1[t][dl]);
    const float4 C0 = *(const float4*)&sC1f[t][0];
    const float4 C1 = *(const float4*)&sC1f[t][4];
    const float4 C2 = *(const float4*)&sC1f[t][8];
    const float4 C3 = *(const float4*)&sC1f[t][12];
    float wb;
    wb  = C0.x * (ex2(AnB[0] * SB) * hB[0]);
    wb += C0.y * (ex2(AnB[1] * SB) * hB[1]);
    wb += C0.z * (ex2(AnB[2] * SB) * hB[2]);
    wb += C0.w * (ex2(AnB[3] * SB) * hB[3]);
    wb += C1.x * (ex2(AnB[4] * SB) * hB[4]);
    wb += C1.y * (ex2(AnB[5] * SB) * hB[5]);
    wb += C1.z * (ex2(AnB[6] * SB) * hB[6]);
    wb += C1.w * (ex2(AnB[7] * SB) * hB[7]);
    wb += C2.x * (ex2(AnB[8] * SB) * hB[8]);
    wb += C2.y * (ex2(AnB[9] * SB) * hB[9]);
    wb += C2.z * (ex2(AnB[10] * SB) * hB[10]);
    wb += C2.w * (ex2(AnB[11] * SB) * hB[11]);
    wb += C3.x * (ex2(AnB[12] * SB) * hB[12]);
    wb += C3.y * (ex2(AnB[13] * SB) * hB[13]);
    wb += C3.z * (ex2(AnB[14] * SB) * hB[14]);
    wb += C3.w * (ex2(AnB[15] * SB) * hB[15]);
    yacc[i] += bf2f(y1p[(size_t)(lbase + t) * D_INNER + d]) + wb;
  }
#pragma unroll
  for (int i = 0; i < 16; ++i) {
    const int l = lbase + tq * 16 + i;
    const float z = bf2f(xz_bf[((size_t)b * L_SEQ + l) * 3072 + 1536 + d]);
    yg[((size_t)b * L_SEQ + l) * D_INNER + d] = f2bf(yacc[i] * z);
  }
}

// ---------------------------------------------------------------------------
extern "C" void kernel_launch(void* const* d_in, const int* in_sizes, int n_in,
                              void* d_out, int out_size, void* d_ws,
                              size_t ws_size, hipStream_t stream) {
  const float* x          = (const float*)d_in[0];
  const float* in_proj_w  = (const float*)d_in[1];
  const float* conv_w     = (const float*)d_in[2];
  const float* conv_b     = (const float*)d_in[3];
  const float* x_proj_w   = (const float*)d_in[4];
  const float* dt_proj_w  = (const float*)d_in[5];
  const float* dt_proj_b  = (const float*)d_in[6];
  const float* A_logs     = (const float*)d_in[7];
  const float* Ds         = (const float*)d_in[8];
  const float* out_proj_w = (const float*)d_in[9];
  float* out = (float*)d_out;

  const int M = MTOT;
  const size_t NST = (size_t)2 * B_SZ * NCH * NDG;  // 3072

  float* ws    = (float*)d_ws;
  float* hfin  = ws;                          // NST*1024
  float* hin   = hfin + NST * 1024;           // NST*1024
  float* Tsum  = hin + NST * 1024;            // NST*64
  float* bcf   = Tsum + NST * 64;             // 2*M*32 f32
  ushort* x_bf     = (ushort*)(bcf + (size_t)2 * M * 32);
  ushort* w_in_bf  = x_bf + (size_t)M * 768;
  ushort* w_out_bf = w_in_bf + (size_t)3072 * 768;
  ushort* w_xp_bf  = w_out_bf + (size_t)768 * 1536;
  ushort* w_dt_bf  = w_xp_bf + (size_t)256 * 1536;
  ushort* xz_bf    = w_dt_bf + (size_t)2 * 1536 * 64;
  ushort* u_bf     = xz_bf + (size_t)M * 3072;
  ushort* delta_bf = u_bf + (size_t)M * 1536;
  ushort* dtin     = delta_bf + (size_t)2 * M * 1536;
  ushort* y_bf     = dtin + (size_t)2 * M * 64;
  ushort* yg_bf    = y_bf + (size_t)2 * M * 1536;

  dim3 blk(256);

  // 0. conversions (one kernel)
  {
    const long TOT = 3145728L + 2359296 + 1179648 + 393216 + 196608;
    cvt_all_kernel<<<dim3((TOT / 4 + 255) / 256), blk, 0, stream>>>(
        x, in_proj_w, out_proj_w, x_proj_w, dt_proj_w, x_bf, w_in_bf, w_out_bf,
        w_xp_bf, w_dt_bf);
  }

  // 1. xz = x @ in_proj_w^T  -> bf16
  gemm_k<128, 128, 0, 1, 0><<<dim3(3072 / 128, M / 128), blk, 0, stream>>>(
      x_bf, 768, w_in_bf, 768, nullptr, xz_bf, 3072, 3072, 768, nullptr,
      nullptr);

  // 2. u = silu(conv(x_conv)+bias) -> bf16
  conv_silu_kernel<<<dim3(B_SZ * (L_SEQ / 8) * (D_INNER / 8) / 256), blk, 0,
                     stream>>>(xz_bf, conv_w, conv_b, u_bf);

  // 3. dtin + bcf(f32) = u @ x_proj_w^T epilogue
  gemm_k<32, 64, 0, 0, 1><<<dim3(3, M / 32), blk, 0, stream>>>(
      u_bf, 1536, w_xp_bf, 1536, nullptr, nullptr, 1, 0, 1536, dtin, bcf);

  // 4. delta = softplus(dtin @ dtw^T + dtb) -> bf16 (both k, one dispatch)
  gemm_dt_k<<<dim3(1536 / 128, M / 64, 2), blk, 0, stream>>>(
      dtin, w_dt_bf, dt_proj_b, delta_bf);

  // 5. scan (block = 256 channels sharing one 64-step chunk, 2 halves)
  scan_local_kernel<<<dim3(2 * B_SZ * 6 * NCH), blk, 0, stream>>>(
      u_bf, bcf, delta_bf, A_logs, Ds, y_bf, hfin, Tsum);
  scan_stitch_kernel<<<dim3(2 * B_SZ * NDG), blk, 0, stream>>>(hfin, Tsum,
                                                               A_logs, hin);
  // 6. fused fixup(both dirs) + gate -> yg bf16
  fixup_gate_kernel<<<dim3(B_SZ * NDG * NCH), blk, 0, stream>>>(
      bcf, delta_bf, A_logs, hin, y_bf, xz_bf, yg_bf);

  // 7. out = yg @ out_proj_w^T -> fp32
  gemm_k<128, 128, 0, 0, 0><<<dim3(768 / 128, M / 128), blk, 0, stream>>>(
      yg_bf, 1536, w_out_bf, 1536, nullptr, out, 768, 768, 1536, nullptr,
      nullptr);
}